// Round 1
// baseline (4247.555 us; speedup 1.0000x reference)
//
#include <hip/hip_runtime.h>
#include <math.h>

// Problem constants
#define BATCH   4096
#define XLEN    1008
#define KSIZE   512     // wavelet kernel
#define NOC1    128     // wavelet out channels
#define NPOS    32      // h positions
#define NOC2    256     // primary caps conv out channels
#define NQ      9       // primary caps positions
#define NCAPS   288     // capsules (256*9/8)
#define NDIM    8
#define NCLS    4
#define NOUT    16

// ws layout (floats):
//   [0,        65536)   w8   : wavelet weights, packed (k1, p, s, i) -> w[2p+s][4k1+i]
//   [65536,   589824)   cwT  : conv weights transposed [ic][k][oc2]
//   [589824, 17367040)  h    : [b][oc][pos] fp32
#define WS_W8   0
#define WS_CWT  65536
#define WS_H    589824

// ---------------- K1a: wavelet weight generation ----------------
__global__ __launch_bounds__(256) void k_wavelet(const float* __restrict__ a,
                                                 const float* __restrict__ w,
                                                 float* __restrict__ w8) {
    int n = blockIdx.x * 256 + threadIdx.x;   // 65536 total
    int k1  = n >> 9;          // 0..127
    int rem = n & 511;
    int p   = rem >> 3;        // 0..63
    int s   = (rem >> 2) & 1;
    int i   = n & 3;
    int oc  = 2 * p + s;
    int k   = 4 * k1 + i;
    float t  = -1.0f + 2.0f * (float)k / 511.0f;
    float av = fmaxf(a[oc], 1e-5f);
    float ts = t / av;
    w8[n] = cosf(w[oc] * t) * expf(-0.5f * ts * ts);
}

// ---------------- K1b: conv_w transpose -> cwT[ic][k][oc2] ----------------
__global__ __launch_bounds__(256) void k_transpose_cw(const float* __restrict__ cw,
                                                      float* __restrict__ cwT) {
    int n = blockIdx.x * 256 + threadIdx.x;   // 524288 total
    int oc2 = n & 255;
    int r   = n >> 8;          // ic*16 + k
    int k   = r & 15;
    int ic  = r >> 4;
    cwT[n] = cw[(oc2 * NOC1 + ic) * 16 + k];
}

// ---------------- K2: WavConv, block per batch ----------------
// thread: q = tid>>6 (pos octet), p = tid&63 (oc pair). 16 accumulators.
__global__ __launch_bounds__(256) void k_wavconv(const float* __restrict__ x,
                                                 const float* __restrict__ w8,
                                                 float* __restrict__ h) {
    int b   = blockIdx.x;
    int tid = threadIdx.x;
    int q   = tid >> 6;   // 0..3
    int p   = tid & 63;   // 0..63

    const float4* xr = (const float4*)(x + (size_t)b * XLEN);
    const float4* wp = (const float4*)w8;

    float acc0[8], acc1[8];
#pragma unroll
    for (int j = 0; j < 8; ++j) { acc0[j] = 0.f; acc1[j] = 0.f; }

    for (int k1 = 0; k1 < 128; ++k1) {
        float4 wa = wp[(k1 * 64 + p) * 2];
        float4 wb = wp[(k1 * 64 + p) * 2 + 1];
#pragma unroll
        for (int j = 0; j < 8; ++j) {
            float4 xv = xr[(q * 8 + j) * 4 + k1];  // wave-uniform broadcast
            acc0[j] = fmaf(wa.x, xv.x, acc0[j]);
            acc0[j] = fmaf(wa.y, xv.y, acc0[j]);
            acc0[j] = fmaf(wa.z, xv.z, acc0[j]);
            acc0[j] = fmaf(wa.w, xv.w, acc0[j]);
            acc1[j] = fmaf(wb.x, xv.x, acc1[j]);
            acc1[j] = fmaf(wb.y, xv.y, acc1[j]);
            acc1[j] = fmaf(wb.z, xv.z, acc1[j]);
            acc1[j] = fmaf(wb.w, xv.w, acc1[j]);
        }
    }

    float* hb = h + (size_t)b * (NOC1 * NPOS);
    float4* hp0 = (float4*)(hb + (2 * p) * NPOS + q * 8);
    float4* hp1 = (float4*)(hb + (2 * p + 1) * NPOS + q * 8);
    hp0[0] = make_float4(acc0[0], acc0[1], acc0[2], acc0[3]);
    hp0[1] = make_float4(acc0[4], acc0[5], acc0[6], acc0[7]);
    hp1[0] = make_float4(acc1[0], acc1[1], acc1[2], acc1[3]);
    hp1[1] = make_float4(acc1[4], acc1[5], acc1[6], acc1[7]);
}

// ---------------- K3: PrimaryCaps conv + squash + u_hat + routing ----------------
// Block handles 4 batches. thread = oc2 for the conv phase.
__global__ __launch_bounds__(256) void k_caps(const float* __restrict__ h,
                                              const float* __restrict__ cwT,
                                              const float* __restrict__ cb,
                                              const float* __restrict__ Wc,
                                              float* __restrict__ out) {
    __shared__ float u_lds[4][NOC2 * NQ];     // p then u (in-place squash): 36864 B
    __shared__ float b_lds[NCAPS * NCLS];     // 4608 B
    __shared__ float c_lds[NCAPS * NCLS];     // 4608 B
    __shared__ float part_lds[256];           // 1024 B
    __shared__ float v_lds[64];               // 256 B

    int tid = threadIdx.x;
    int b0  = blockIdx.x * 4;

    // ---- Phase C: PrimaryCaps conv, thread = oc2, 4 batches x 9 q accumulators
    float acc[4][NQ];
    {
        float bias = cb[tid];
#pragma unroll
        for (int b = 0; b < 4; ++b)
#pragma unroll
            for (int q = 0; q < NQ; ++q) acc[b][q] = bias;
    }

    for (int ic = 0; ic < NOC1; ++ic) {
        float wreg[16];
#pragma unroll
        for (int k = 0; k < 16; ++k)
            wreg[k] = cwT[(ic * 16 + k) * NOC2 + tid];
#pragma unroll
        for (int b = 0; b < 4; ++b) {
            const float4* hr = (const float4*)(h + ((size_t)(b0 + b) * NOC1 + ic) * NPOS);
            float row[32];
#pragma unroll
            for (int r = 0; r < 8; ++r) ((float4*)row)[r] = hr[r];
#pragma unroll
            for (int q = 0; q < NQ; ++q)
#pragma unroll
                for (int k = 0; k < 16; ++k)
                    acc[b][q] = fmaf(wreg[k], row[2 * q + k], acc[b][q]);
        }
    }

    // write p to LDS
#pragma unroll
    for (int b = 0; b < 4; ++b)
#pragma unroll
        for (int q = 0; q < NQ; ++q)
            u_lds[b][tid * NQ + q] = acc[b][q];
    __syncthreads();

    // ---- Phase D: squash -> u (in place)
    for (int idx = tid; idx < 4 * NCAPS; idx += 256) {
        int b = idx / NCAPS;
        int c = idx - b * NCAPS;
        float* pp = &u_lds[b][c * NDIM];
        float sn = 0.f;
#pragma unroll
        for (int i = 0; i < NDIM; ++i) sn = fmaf(pp[i], pp[i], sn);
        float sc = sn / (1.f + sn) / sqrtf(sn + 1e-8f);
#pragma unroll
        for (int i = 0; i < NDIM; ++i) pp[i] *= sc;
    }
    __syncthreads();

    // ---- Phase E: u_hat + dynamic routing, per batch
    int g = tid >> 6;     // wave id: capsule group
    int l = tid & 63;
    int d = l >> 4;       // class 0..3
    int o = l & 15;       // out dim 0..15

    for (int b = 0; b < 4; ++b) {
        // u_hat[c] for capsules g*72 .. g*72+71, this (d,o)
        float uh[72];
        const float* ub = u_lds[b];
#pragma unroll
        for (int c = 0; c < 72; ++c) {
            int cap = g * 72 + c;
            const float4* W4 = (const float4*)(Wc + ((size_t)cap * 512) + l * 8);
            float4 A  = W4[0];
            float4 Bv = W4[1];
            const float4* uu = (const float4*)(ub + cap * NDIM);
            float4 u0 = uu[0], u1 = uu[1];
            float t = A.x * u0.x;
            t = fmaf(A.y,  u0.y, t);
            t = fmaf(A.z,  u0.z, t);
            t = fmaf(A.w,  u0.w, t);
            t = fmaf(Bv.x, u1.x, t);
            t = fmaf(Bv.y, u1.y, t);
            t = fmaf(Bv.z, u1.z, t);
            t = fmaf(Bv.w, u1.w, t);
            uh[c] = t;
        }

        // zero b_ij
        for (int i2 = tid; i2 < NCAPS * NCLS; i2 += 256) b_lds[i2] = 0.f;
        __syncthreads();

        for (int r = 0; r < 3; ++r) {
            // softmax over classes; also emit c_ij output on last iter
            for (int c = tid; c < NCAPS; c += 256) {
                float x0 = b_lds[c * 4 + 0];
                float x1 = b_lds[c * 4 + 1];
                float x2 = b_lds[c * 4 + 2];
                float x3 = b_lds[c * 4 + 3];
                float m  = fmaxf(fmaxf(x0, x1), fmaxf(x2, x3));
                float e0 = expf(x0 - m), e1 = expf(x1 - m);
                float e2 = expf(x2 - m), e3 = expf(x3 - m);
                float inv = 1.f / (e0 + e1 + e2 + e3);
                e0 *= inv; e1 *= inv; e2 *= inv; e3 *= inv;
                c_lds[c * 4 + 0] = e0;
                c_lds[c * 4 + 1] = e1;
                c_lds[c * 4 + 2] = e2;
                c_lds[c * 4 + 3] = e3;
                if (r == 2) {
                    *(float4*)(out + 16384 + ((size_t)(b0 + b) * NCAPS + c) * 4) =
                        make_float4(e0, e1, e2, e3);
                }
            }
            __syncthreads();

            // s_j partial: sum over this wave's 72 capsules
            float partv = 0.f;
#pragma unroll
            for (int c = 0; c < 72; ++c)
                partv = fmaf(c_lds[(g * 72 + c) * 4 + d], uh[c], partv);
            part_lds[tid] = partv;
            __syncthreads();

            if (tid < 64) {
                float sv = part_lds[tid] + part_lds[tid + 64] +
                           part_lds[tid + 128] + part_lds[tid + 192];
                // squash over the 16 o-lanes
                float sq = sv * sv;
                sq += __shfl_xor(sq, 1);
                sq += __shfl_xor(sq, 2);
                sq += __shfl_xor(sq, 4);
                sq += __shfl_xor(sq, 8);
                float sc = sq / (1.f + sq) / sqrtf(sq + 1e-8f);
                float v  = sv * sc;
                v_lds[tid] = v;
                if (r == 2) {
                    float vv = v * v;
                    vv += __shfl_xor(vv, 1);
                    vv += __shfl_xor(vv, 2);
                    vv += __shfl_xor(vv, 4);
                    vv += __shfl_xor(vv, 8);
                    if ((tid & 15) == 0)
                        out[(size_t)(b0 + b) * 4 + (tid >> 4)] = sqrtf(vv);
                }
            }
            __syncthreads();

            if (r < 2) {
                float vv = v_lds[l];
#pragma unroll
                for (int c = 0; c < 72; ++c) {
                    float t = uh[c] * vv;
                    t += __shfl_xor(t, 1);
                    t += __shfl_xor(t, 2);
                    t += __shfl_xor(t, 4);
                    t += __shfl_xor(t, 8);
                    if (o == 0) b_lds[(g * 72 + c) * 4 + d] += t;
                }
                __syncthreads();
            }
        }
        __syncthreads();
    }
}

extern "C" void kernel_launch(void* const* d_in, const int* in_sizes, int n_in,
                              void* d_out, int out_size, void* d_ws, size_t ws_size,
                              hipStream_t stream) {
    const float* x      = (const float*)d_in[0];
    const float* a      = (const float*)d_in[1];
    const float* w      = (const float*)d_in[2];
    const float* conv_w = (const float*)d_in[3];
    const float* conv_b = (const float*)d_in[4];
    const float* W_caps = (const float*)d_in[5];
    float* out = (float*)d_out;
    float* ws  = (float*)d_ws;

    float* w8  = ws + WS_W8;
    float* cwT = ws + WS_CWT;
    float* h   = ws + WS_H;

    k_wavelet<<<256, 256, 0, stream>>>(a, w, w8);
    k_transpose_cw<<<2048, 256, 0, stream>>>(conv_w, cwT);
    k_wavconv<<<BATCH, 256, 0, stream>>>(x, w8, h);
    k_caps<<<BATCH / 4, 256, 0, stream>>>(h, cwT, conv_b, W_caps, out);
}

// Round 2
// 2804.236 us; speedup vs baseline: 1.5147x; 1.5147x over previous
//
#include <hip/hip_runtime.h>
#include <hip/hip_bf16.h>
#include <math.h>

typedef __attribute__((ext_vector_type(8))) short short8;
typedef __attribute__((ext_vector_type(4))) float f32x4;

#define BATCH   4096
#define XLEN    1008
#define NOC1    128
#define NPOS    32
#define NOC2    256
#define NQ      9
#define NCAPS   288
#define NDIM    8

// ws layout (bytes)
#define W8_OFF    0           // fp32 wavelet weights, 262144 B
#define BPH_OFF   262144      // B-pack hi bf16, 1 MB
#define BPL_OFF   1310720     // B-pack lo bf16, 1 MB
#define H2HI_OFF  2359296     // h2 hi bf16 [b][pos32][ic128], 33.55 MB
#define H2LO_OFF  35913728    // h2 lo bf16, 33.55 MB
#define U_OFF     69468160    // u fp32 [b][288][8], 37.75 MB

// ---------------- K1a: wavelet weight generation (packed for k_wavconv) ----
__global__ __launch_bounds__(256) void k_wavelet(const float* __restrict__ a,
                                                 const float* __restrict__ w,
                                                 float* __restrict__ w8) {
    int n = blockIdx.x * 256 + threadIdx.x;   // 65536 total
    int k1  = n >> 9;
    int rem = n & 511;
    int p   = rem >> 3;
    int s   = (rem >> 2) & 1;
    int i   = n & 3;
    int oc  = 2 * p + s;
    int k   = 4 * k1 + i;
    float t  = -1.0f + 2.0f * (float)k / 511.0f;
    float av = fmaxf(a[oc], 1e-5f);
    float ts = t / av;
    w8[n] = cosf(w[oc] * t) * expf(-0.5f * ts * ts);
}

// ---------------- K1b: pack conv_w into MFMA B-fragment order, bf16 hi/lo --
// Bpack[nt][s][lane][e] = conv_w[n=nt*16+(lane&15)][ic=(s&3)*32+(lane>>4)*8+e][kk=s>>2]
__global__ __launch_bounds__(256) void k_pack_b(const float* __restrict__ cw,
                                                __hip_bfloat16* __restrict__ bh,
                                                __hip_bfloat16* __restrict__ bl) {
    int o = blockIdx.x * 256 + threadIdx.x;   // 524288 total
    int e    = o & 7;
    int lane = (o >> 3) & 63;
    int s    = (o >> 9) & 63;
    int nt   = o >> 15;
    int n  = nt * 16 + (lane & 15);
    int j  = lane >> 4;
    int kk = s >> 2;
    int ic = (s & 3) * 32 + j * 8 + e;
    float v = cw[(n * NOC1 + ic) * 16 + kk];
    __hip_bfloat16 h = __float2bfloat16(v);
    bh[o] = h;
    bl[o] = __float2bfloat16(v - __bfloat162float(h));
}

// ---------------- K2: WavConv fp32, emits h2 hi/lo bf16 [b][pos][ic] -------
__global__ __launch_bounds__(256) void k_wavconv(const float* __restrict__ x,
                                                 const float* __restrict__ w8,
                                                 __hip_bfloat16* __restrict__ h2hi,
                                                 __hip_bfloat16* __restrict__ h2lo) {
    int b   = blockIdx.x;
    int tid = threadIdx.x;
    int q   = tid >> 6;   // 0..3
    int p   = tid & 63;   // 0..63

    const float4* xr = (const float4*)(x + (size_t)b * XLEN);
    const float4* wp = (const float4*)w8;

    float acc0[8], acc1[8];
#pragma unroll
    for (int j = 0; j < 8; ++j) { acc0[j] = 0.f; acc1[j] = 0.f; }

    for (int k1 = 0; k1 < 128; ++k1) {
        float4 wa = wp[(k1 * 64 + p) * 2];
        float4 wb = wp[(k1 * 64 + p) * 2 + 1];
#pragma unroll
        for (int j = 0; j < 8; ++j) {
            float4 xv = xr[(q * 8 + j) * 4 + k1];  // wave-uniform broadcast
            acc0[j] = fmaf(wa.x, xv.x, acc0[j]);
            acc0[j] = fmaf(wa.y, xv.y, acc0[j]);
            acc0[j] = fmaf(wa.z, xv.z, acc0[j]);
            acc0[j] = fmaf(wa.w, xv.w, acc0[j]);
            acc1[j] = fmaf(wb.x, xv.x, acc1[j]);
            acc1[j] = fmaf(wb.y, xv.y, acc1[j]);
            acc1[j] = fmaf(wb.z, xv.z, acc1[j]);
            acc1[j] = fmaf(wb.w, xv.w, acc1[j]);
        }
    }

    __hip_bfloat16* hh = h2hi + (size_t)b * (NPOS * NOC1);
    __hip_bfloat16* hl = h2lo + (size_t)b * (NPOS * NOC1);
#pragma unroll
    for (int j = 0; j < 8; ++j) {
        int pos = q * 8 + j;
        float v0 = acc0[j], v1 = acc1[j];
        __hip_bfloat16 h0 = __float2bfloat16(v0);
        __hip_bfloat16 h1 = __float2bfloat16(v1);
        __hip_bfloat162 hv; hv.x = h0; hv.y = h1;
        __hip_bfloat162 lv;
        lv.x = __float2bfloat16(v0 - __bfloat162float(h0));
        lv.y = __float2bfloat16(v1 - __bfloat162float(h1));
        *(__hip_bfloat162*)(hh + pos * NOC1 + 2 * p) = hv;
        *(__hip_bfloat162*)(hl + pos * NOC1 + 2 * p) = lv;
    }
}

// ---------------- K3: PrimaryCaps conv via bf16 MFMA (3-term split) + squash
// Block: 16 batches, 512 threads (8 waves). M = 9 m-tiles (m = q*16+b_local),
// N = 16 n-tiles (wave w owns tiles w and 8+w), K = 2048 in 64 steps of 32.
// k-step s: kk = s>>2, ic base = (s&3)*32, k-local = ic offset 0..31.
__global__ __launch_bounds__(512) void k_conv_mfma(const __hip_bfloat16* __restrict__ h2hi,
                                                   const __hip_bfloat16* __restrict__ h2lo,
                                                   const __hip_bfloat16* __restrict__ bph,
                                                   const __hip_bfloat16* __restrict__ bpl,
                                                   const float* __restrict__ cb,
                                                   float* __restrict__ u) {
    __shared__ float smem[18432];            // 73728 B: A-staging, then p-exchange
    short* Alds  = (short*)smem;             // [2 variants][144 m][stride 40]
    float* p_lds = smem;                     // [16 b][1152 = oc2l*9+q]

    int tid  = threadIdx.x;
    int w    = tid >> 6;
    int lane = tid & 63;
    int col  = lane & 15;
    int rg   = lane >> 4;
    int b0   = blockIdx.x * 16;

    f32x4 acc0[9], acc1[9];
    f32x4 z = {0.f, 0.f, 0.f, 0.f};
#pragma unroll
    for (int mt = 0; mt < 9; ++mt) { acc0[mt] = z; acc1[mt] = z; }

    for (int s = 0; s < 64; ++s) {
        int kk  = s >> 2;
        int icb = (s & 3) * 32;
        __syncthreads();
        // stage A-chunk (hi+lo): 144 rows x 32 elems each variant
        for (int idx = tid; idx < 1152; idx += 512) {
            int v  = idx >= 576;
            int j2 = idx - v * 576;
            int m  = j2 >> 2;
            int g  = j2 & 3;
            const __hip_bfloat16* src = (v ? h2lo : h2hi) +
                ((size_t)(b0 + (m & 15)) * NPOS + (2 * (m >> 4) + kk)) * NOC1 + icb + g * 8;
            short8 val = *(const short8*)src;
            *(short8*)&Alds[v * 5760 + m * 40 + g * 8] = val;
        }
        __syncthreads();

        // B fragments for this wave's two n-tiles (prepacked, coalesced 16B/lane)
        size_t bo0 = ((size_t)(w * 64 + s) * 64 + lane) * 8;
        size_t bo1 = ((size_t)((8 + w) * 64 + s) * 64 + lane) * 8;
        short8 b0h = *(const short8*)(bph + bo0);
        short8 b0l = *(const short8*)(bpl + bo0);
        short8 b1h = *(const short8*)(bph + bo1);
        short8 b1l = *(const short8*)(bpl + bo1);

#pragma unroll
        for (int mt = 0; mt < 9; ++mt) {
            int aoff = (mt * 16 + col) * 40 + rg * 8;
            short8 ah = *(const short8*)&Alds[aoff];
            short8 al = *(const short8*)&Alds[5760 + aoff];
            acc0[mt] = __builtin_amdgcn_mfma_f32_16x16x32_bf16(ah, b0h, acc0[mt], 0, 0, 0);
            acc0[mt] = __builtin_amdgcn_mfma_f32_16x16x32_bf16(ah, b0l, acc0[mt], 0, 0, 0);
            acc0[mt] = __builtin_amdgcn_mfma_f32_16x16x32_bf16(al, b0h, acc0[mt], 0, 0, 0);
            acc1[mt] = __builtin_amdgcn_mfma_f32_16x16x32_bf16(ah, b1h, acc1[mt], 0, 0, 0);
            acc1[mt] = __builtin_amdgcn_mfma_f32_16x16x32_bf16(ah, b1l, acc1[mt], 0, 0, 0);
            acc1[mt] = __builtin_amdgcn_mfma_f32_16x16x32_bf16(al, b1h, acc1[mt], 0, 0, 0);
        }
    }
    __syncthreads();

    // Epilogue: per 128-oc2 chunk: p -> LDS, +bias, squash, u -> global.
    // C/D layout: col = lane&15 (n within tile), row = rg*4 + reg (b within tile).
    for (int ch = 0; ch < 2; ++ch) {
        int oc2l = w * 16 + col;                  // chunk-local oc2 (tile = ch*8+w)
        float bias = cb[ch * 128 + oc2l];
        f32x4* accp = ch ? acc1 : acc0;
#pragma unroll
        for (int mt = 0; mt < 9; ++mt)
#pragma unroll
            for (int r = 0; r < 4; ++r) {
                int b = rg * 4 + r;
                p_lds[b * 1152 + oc2l * 9 + mt] = accp[mt][r] + bias;
            }
        __syncthreads();
        for (int idx = tid; idx < 2304; idx += 512) {   // 16 b x 144 caps
            int b  = idx / 144;
            int cl = idx - b * 144;
            float* pp = &p_lds[b * 1152 + cl * 8];
            float sn = 0.f;
#pragma unroll
            for (int i = 0; i < NDIM; ++i) sn = fmaf(pp[i], pp[i], sn);
            float sc = sn / (1.f + sn) / sqrtf(sn + 1e-8f);
            float* ug = u + ((size_t)(b0 + b) * (NCAPS * NDIM) + (ch * 144 + cl) * 8);
            float4 u0 = make_float4(pp[0] * sc, pp[1] * sc, pp[2] * sc, pp[3] * sc);
            float4 u1 = make_float4(pp[4] * sc, pp[5] * sc, pp[6] * sc, pp[7] * sc);
            ((float4*)ug)[0] = u0;
            ((float4*)ug)[1] = u1;
        }
        __syncthreads();
    }
}

// ---------------- K4: u_hat + dynamic routing, 4 batches/block -------------
__global__ __launch_bounds__(256) void k_routing(const float* __restrict__ u,
                                                 const float* __restrict__ Wc,
                                                 float* __restrict__ out) {
    __shared__ float u_lds[4][NCAPS * NDIM];   // 36864 B
    __shared__ float b_lds[NCAPS * 4];         // 4608 B
    __shared__ float c_lds[NCAPS * 4];         // 4608 B
    __shared__ float part_lds[256];
    __shared__ float v_lds[64];

    int tid = threadIdx.x;
    int b0  = blockIdx.x * 4;

    // load u for 4 batches
    {
        const float4* ug = (const float4*)(u + (size_t)b0 * (NCAPS * NDIM));
        float4* ul = (float4*)u_lds;
        for (int i = tid; i < 4 * NCAPS * NDIM / 4; i += 256) ul[i] = ug[i];
    }
    __syncthreads();

    int g = tid >> 6;     // wave id: capsule group (72 caps each)
    int l = tid & 63;
    int d = l >> 4;       // class
    int o = l & 15;       // out dim

    for (int b = 0; b < 4; ++b) {
        float uh[72];
        const float* ub = u_lds[b];
#pragma unroll
        for (int c = 0; c < 72; ++c) {
            int cap = g * 72 + c;
            const float4* W4 = (const float4*)(Wc + ((size_t)cap * 512) + l * 8);
            float4 A  = W4[0];
            float4 Bv = W4[1];
            const float4* uu = (const float4*)(ub + cap * NDIM);
            float4 u0 = uu[0], u1 = uu[1];
            float t = A.x * u0.x;
            t = fmaf(A.y,  u0.y, t);
            t = fmaf(A.z,  u0.z, t);
            t = fmaf(A.w,  u0.w, t);
            t = fmaf(Bv.x, u1.x, t);
            t = fmaf(Bv.y, u1.y, t);
            t = fmaf(Bv.z, u1.z, t);
            t = fmaf(Bv.w, u1.w, t);
            uh[c] = t;
        }

        for (int i2 = tid; i2 < NCAPS * 4; i2 += 256) b_lds[i2] = 0.f;
        __syncthreads();

        for (int r = 0; r < 3; ++r) {
            for (int c = tid; c < NCAPS; c += 256) {
                float x0 = b_lds[c * 4 + 0];
                float x1 = b_lds[c * 4 + 1];
                float x2 = b_lds[c * 4 + 2];
                float x3 = b_lds[c * 4 + 3];
                float m  = fmaxf(fmaxf(x0, x1), fmaxf(x2, x3));
                float e0 = expf(x0 - m), e1 = expf(x1 - m);
                float e2 = expf(x2 - m), e3 = expf(x3 - m);
                float inv = 1.f / (e0 + e1 + e2 + e3);
                e0 *= inv; e1 *= inv; e2 *= inv; e3 *= inv;
                c_lds[c * 4 + 0] = e0;
                c_lds[c * 4 + 1] = e1;
                c_lds[c * 4 + 2] = e2;
                c_lds[c * 4 + 3] = e3;
                if (r == 2) {
                    *(float4*)(out + 16384 + ((size_t)(b0 + b) * NCAPS + c) * 4) =
                        make_float4(e0, e1, e2, e3);
                }
            }
            __syncthreads();

            float partv = 0.f;
#pragma unroll
            for (int c = 0; c < 72; ++c)
                partv = fmaf(c_lds[(g * 72 + c) * 4 + d], uh[c], partv);
            part_lds[tid] = partv;
            __syncthreads();

            if (tid < 64) {
                float sv = part_lds[tid] + part_lds[tid + 64] +
                           part_lds[tid + 128] + part_lds[tid + 192];
                float sq = sv * sv;
                sq += __shfl_xor(sq, 1);
                sq += __shfl_xor(sq, 2);
                sq += __shfl_xor(sq, 4);
                sq += __shfl_xor(sq, 8);
                float sc = sq / (1.f + sq) / sqrtf(sq + 1e-8f);
                float v  = sv * sc;
                v_lds[tid] = v;
                if (r == 2) {
                    float vv = v * v;
                    vv += __shfl_xor(vv, 1);
                    vv += __shfl_xor(vv, 2);
                    vv += __shfl_xor(vv, 4);
                    vv += __shfl_xor(vv, 8);
                    if ((tid & 15) == 0)
                        out[(size_t)(b0 + b) * 4 + (tid >> 4)] = sqrtf(vv);
                }
            }
            __syncthreads();

            if (r < 2) {
                float vv = v_lds[l];
#pragma unroll
                for (int c = 0; c < 72; ++c) {
                    float t = uh[c] * vv;
                    t += __shfl_xor(t, 1);
                    t += __shfl_xor(t, 2);
                    t += __shfl_xor(t, 4);
                    t += __shfl_xor(t, 8);
                    if (o == 0) b_lds[(g * 72 + c) * 4 + d] += t;
                }
                __syncthreads();
            }
        }
        __syncthreads();
    }
}

extern "C" void kernel_launch(void* const* d_in, const int* in_sizes, int n_in,
                              void* d_out, int out_size, void* d_ws, size_t ws_size,
                              hipStream_t stream) {
    const float* x      = (const float*)d_in[0];
    const float* a      = (const float*)d_in[1];
    const float* w      = (const float*)d_in[2];
    const float* conv_w = (const float*)d_in[3];
    const float* conv_b = (const float*)d_in[4];
    const float* W_caps = (const float*)d_in[5];
    float* out = (float*)d_out;
    char* ws   = (char*)d_ws;

    float*           w8   = (float*)(ws + W8_OFF);
    __hip_bfloat16*  bph  = (__hip_bfloat16*)(ws + BPH_OFF);
    __hip_bfloat16*  bpl  = (__hip_bfloat16*)(ws + BPL_OFF);
    __hip_bfloat16*  h2hi = (__hip_bfloat16*)(ws + H2HI_OFF);
    __hip_bfloat16*  h2lo = (__hip_bfloat16*)(ws + H2LO_OFF);
    float*           u    = (float*)(ws + U_OFF);

    k_wavelet<<<256, 256, 0, stream>>>(a, w, w8);
    k_pack_b<<<2048, 256, 0, stream>>>(conv_w, bph, bpl);
    k_wavconv<<<BATCH, 256, 0, stream>>>(x, w8, h2hi, h2lo);
    k_conv_mfma<<<BATCH / 16, 512, 0, stream>>>(h2hi, h2lo, bph, bpl, conv_b, u);
    k_routing<<<BATCH / 4, 256, 0, stream>>>(u, W_caps, out);
}

// Round 3
// 992.890 us; speedup vs baseline: 4.2780x; 2.8243x over previous
//
#include <hip/hip_runtime.h>
#include <hip/hip_bf16.h>
#include <math.h>

typedef __attribute__((ext_vector_type(8))) short short8;
typedef __attribute__((ext_vector_type(4))) float f32x4;

#define BATCH   4096
#define XLEN    1008
#define NOC1    128
#define NPOS    32
#define NOC2    256
#define NQ      9
#define NCAPS   288
#define NDIM    8

// ws layout (bytes)
#define W8_OFF    0           // fp32 wavelet weights, 262144 B
#define BPH_OFF   262144      // B-pack hi bf16, 1 MB
#define BPL_OFF   1310720     // B-pack lo bf16, 1 MB
#define H2HI_OFF  2359296     // h2 hi bf16 [b][pos32][ic128], 33.55 MB
#define H2LO_OFF  35913728    // h2 lo bf16, 33.55 MB
#define U_OFF     69468160    // u fp32 [b][288][8], 37.75 MB

// ---------------- K1a: wavelet weight generation (packed for k_wavconv) ----
__global__ __launch_bounds__(256) void k_wavelet(const float* __restrict__ a,
                                                 const float* __restrict__ w,
                                                 float* __restrict__ w8) {
    int n = blockIdx.x * 256 + threadIdx.x;   // 65536 total
    int k1  = n >> 9;
    int rem = n & 511;
    int p   = rem >> 3;
    int s   = (rem >> 2) & 1;
    int i   = n & 3;
    int oc  = 2 * p + s;
    int k   = 4 * k1 + i;
    float t  = -1.0f + 2.0f * (float)k / 511.0f;
    float av = fmaxf(a[oc], 1e-5f);
    float ts = t / av;
    w8[n] = cosf(w[oc] * t) * expf(-0.5f * ts * ts);
}

// ---------------- K1b: pack conv_w into MFMA B-fragment order, bf16 hi/lo --
// Bpack[nt][s][lane][e] = conv_w[n=nt*16+(lane&15)][ic=(s&3)*32+(lane>>4)*8+e][kk=s>>2]
__global__ __launch_bounds__(256) void k_pack_b(const float* __restrict__ cw,
                                                __hip_bfloat16* __restrict__ bh,
                                                __hip_bfloat16* __restrict__ bl) {
    int o = blockIdx.x * 256 + threadIdx.x;   // 524288 total
    int e    = o & 7;
    int lane = (o >> 3) & 63;
    int s    = (o >> 9) & 63;
    int nt   = o >> 15;
    int n  = nt * 16 + (lane & 15);
    int j  = lane >> 4;
    int kk = s >> 2;
    int ic = (s & 3) * 32 + j * 8 + e;
    float v = cw[(n * NOC1 + ic) * 16 + kk];
    __hip_bfloat16 h = __float2bfloat16(v);
    bh[o] = h;
    bl[o] = __float2bfloat16(v - __bfloat162float(h));
}

// ---------------- K2: WavConv fp32, emits h2 hi/lo bf16 [b][pos][ic] -------
__global__ __launch_bounds__(256) void k_wavconv(const float* __restrict__ x,
                                                 const float* __restrict__ w8,
                                                 __hip_bfloat16* __restrict__ h2hi,
                                                 __hip_bfloat16* __restrict__ h2lo) {
    int b   = blockIdx.x;
    int tid = threadIdx.x;
    int q   = tid >> 6;   // 0..3
    int p   = tid & 63;   // 0..63

    const float4* xr = (const float4*)(x + (size_t)b * XLEN);
    const float4* wp = (const float4*)w8;

    float acc0[8], acc1[8];
#pragma unroll
    for (int j = 0; j < 8; ++j) { acc0[j] = 0.f; acc1[j] = 0.f; }

    for (int k1 = 0; k1 < 128; ++k1) {
        float4 wa = wp[(k1 * 64 + p) * 2];
        float4 wb = wp[(k1 * 64 + p) * 2 + 1];
#pragma unroll
        for (int j = 0; j < 8; ++j) {
            float4 xv = xr[(q * 8 + j) * 4 + k1];  // wave-uniform broadcast
            acc0[j] = fmaf(wa.x, xv.x, acc0[j]);
            acc0[j] = fmaf(wa.y, xv.y, acc0[j]);
            acc0[j] = fmaf(wa.z, xv.z, acc0[j]);
            acc0[j] = fmaf(wa.w, xv.w, acc0[j]);
            acc1[j] = fmaf(wb.x, xv.x, acc1[j]);
            acc1[j] = fmaf(wb.y, xv.y, acc1[j]);
            acc1[j] = fmaf(wb.z, xv.z, acc1[j]);
            acc1[j] = fmaf(wb.w, xv.w, acc1[j]);
        }
    }

    __hip_bfloat16* hh = h2hi + (size_t)b * (NPOS * NOC1);
    __hip_bfloat16* hl = h2lo + (size_t)b * (NPOS * NOC1);
#pragma unroll
    for (int j = 0; j < 8; ++j) {
        int pos = q * 8 + j;
        float v0 = acc0[j], v1 = acc1[j];
        __hip_bfloat16 h0 = __float2bfloat16(v0);
        __hip_bfloat16 h1 = __float2bfloat16(v1);
        __hip_bfloat162 hv; hv.x = h0; hv.y = h1;
        __hip_bfloat162 lv;
        lv.x = __float2bfloat16(v0 - __bfloat162float(h0));
        lv.y = __float2bfloat16(v1 - __bfloat162float(h1));
        *(__hip_bfloat162*)(hh + pos * NOC1 + 2 * p) = hv;
        *(__hip_bfloat162*)(hl + pos * NOC1 + 2 * p) = lv;
    }
}

// ---------------- K3: PrimaryCaps conv via bf16 MFMA (3-term split) + squash
__global__ __launch_bounds__(512) void k_conv_mfma(const __hip_bfloat16* __restrict__ h2hi,
                                                   const __hip_bfloat16* __restrict__ h2lo,
                                                   const __hip_bfloat16* __restrict__ bph,
                                                   const __hip_bfloat16* __restrict__ bpl,
                                                   const float* __restrict__ cb,
                                                   float* __restrict__ u) {
    __shared__ float smem[18432];            // 73728 B: A-staging, then p-exchange
    short* Alds  = (short*)smem;             // [2 variants][144 m][stride 40]
    float* p_lds = smem;                     // [16 b][1152 = oc2l*9+q]

    int tid  = threadIdx.x;
    int w    = tid >> 6;
    int lane = tid & 63;
    int col  = lane & 15;
    int rg   = lane >> 4;
    int b0   = blockIdx.x * 16;

    f32x4 acc0[9], acc1[9];
    f32x4 z = {0.f, 0.f, 0.f, 0.f};
#pragma unroll
    for (int mt = 0; mt < 9; ++mt) { acc0[mt] = z; acc1[mt] = z; }

    for (int s = 0; s < 64; ++s) {
        int kk  = s >> 2;
        int icb = (s & 3) * 32;
        __syncthreads();
        for (int idx = tid; idx < 1152; idx += 512) {
            int v  = idx >= 576;
            int j2 = idx - v * 576;
            int m  = j2 >> 2;
            int g  = j2 & 3;
            const __hip_bfloat16* src = (v ? h2lo : h2hi) +
                ((size_t)(b0 + (m & 15)) * NPOS + (2 * (m >> 4) + kk)) * NOC1 + icb + g * 8;
            short8 val = *(const short8*)src;
            *(short8*)&Alds[v * 5760 + m * 40 + g * 8] = val;
        }
        __syncthreads();

        size_t bo0 = ((size_t)(w * 64 + s) * 64 + lane) * 8;
        size_t bo1 = ((size_t)((8 + w) * 64 + s) * 64 + lane) * 8;
        short8 b0h = *(const short8*)(bph + bo0);
        short8 b0l = *(const short8*)(bpl + bo0);
        short8 b1h = *(const short8*)(bph + bo1);
        short8 b1l = *(const short8*)(bpl + bo1);

#pragma unroll
        for (int mt = 0; mt < 9; ++mt) {
            int aoff = (mt * 16 + col) * 40 + rg * 8;
            short8 ah = *(const short8*)&Alds[aoff];
            short8 al = *(const short8*)&Alds[5760 + aoff];
            acc0[mt] = __builtin_amdgcn_mfma_f32_16x16x32_bf16(ah, b0h, acc0[mt], 0, 0, 0);
            acc0[mt] = __builtin_amdgcn_mfma_f32_16x16x32_bf16(ah, b0l, acc0[mt], 0, 0, 0);
            acc0[mt] = __builtin_amdgcn_mfma_f32_16x16x32_bf16(al, b0h, acc0[mt], 0, 0, 0);
            acc1[mt] = __builtin_amdgcn_mfma_f32_16x16x32_bf16(ah, b1h, acc1[mt], 0, 0, 0);
            acc1[mt] = __builtin_amdgcn_mfma_f32_16x16x32_bf16(ah, b1l, acc1[mt], 0, 0, 0);
            acc1[mt] = __builtin_amdgcn_mfma_f32_16x16x32_bf16(al, b1h, acc1[mt], 0, 0, 0);
        }
    }
    __syncthreads();

    for (int ch = 0; ch < 2; ++ch) {
        int oc2l = w * 16 + col;
        float bias = cb[ch * 128 + oc2l];
        f32x4* accp = ch ? acc1 : acc0;
#pragma unroll
        for (int mt = 0; mt < 9; ++mt)
#pragma unroll
            for (int r = 0; r < 4; ++r) {
                int b = rg * 4 + r;
                p_lds[b * 1152 + oc2l * 9 + mt] = accp[mt][r] + bias;
            }
        __syncthreads();
        for (int idx = tid; idx < 2304; idx += 512) {
            int b  = idx / 144;
            int cl = idx - b * 144;
            float* pp = &p_lds[b * 1152 + cl * 8];
            float sn = 0.f;
#pragma unroll
            for (int i = 0; i < NDIM; ++i) sn = fmaf(pp[i], pp[i], sn);
            float sc = sn / (1.f + sn) / sqrtf(sn + 1e-8f);
            float* ug = u + ((size_t)(b0 + b) * (NCAPS * NDIM) + (ch * 144 + cl) * 8);
            float4 u0 = make_float4(pp[0] * sc, pp[1] * sc, pp[2] * sc, pp[3] * sc);
            float4 u1 = make_float4(pp[4] * sc, pp[5] * sc, pp[6] * sc, pp[7] * sc);
            ((float4*)ug)[0] = u0;
            ((float4*)ug)[1] = u1;
        }
        __syncthreads();
    }
}

// ---------------- K4: u_hat + dynamic routing, 1 batch/block, 512 threads --
// 8 waves; wave g owns capsules [g*36, g*36+36). lane l -> (d = l>>4, o = l&15).
__global__ __launch_bounds__(512, 4) void k_routing(const float* __restrict__ u,
                                                    const float* __restrict__ Wc,
                                                    float* __restrict__ out) {
    __shared__ float u_lds[NCAPS * NDIM];   // 9216 B
    __shared__ float b_lds[NCAPS * 4];      // 4608 B
    __shared__ float c_lds[NCAPS * 4];      // 4608 B
    __shared__ float part_lds[512];         // 2048 B
    __shared__ float v_lds[64];             // 256 B

    int tid = threadIdx.x;
    int b   = blockIdx.x;

    // stage u (one batch: 2304 floats) + zero b_ij
    {
        const float4* ug = (const float4*)(u + (size_t)b * (NCAPS * NDIM));
        float4* ul = (float4*)u_lds;
        for (int i = tid; i < NCAPS * NDIM / 4; i += 512) ul[i] = ug[i];
    }
    for (int i = tid; i < NCAPS * 4; i += 512) b_lds[i] = 0.f;
    __syncthreads();

    int g = tid >> 6;     // wave id: 36-capsule group
    int l = tid & 63;
    int d = l >> 4;       // class
    int o = l & 15;       // out dim

    // u_hat for this thread's 36 capsules at (d,o)
    float uh[36];
#pragma unroll
    for (int c = 0; c < 36; ++c) {
        int cap = g * 36 + c;
        const float4* W4 = (const float4*)(Wc + ((size_t)cap * 512) + l * 8);
        float4 A  = W4[0];
        float4 Bv = W4[1];
        const float4* uu = (const float4*)(u_lds + cap * NDIM);
        float4 u0 = uu[0], u1 = uu[1];
        float t = A.x * u0.x;
        t = fmaf(A.y,  u0.y, t);
        t = fmaf(A.z,  u0.z, t);
        t = fmaf(A.w,  u0.w, t);
        t = fmaf(Bv.x, u1.x, t);
        t = fmaf(Bv.y, u1.y, t);
        t = fmaf(Bv.z, u1.z, t);
        t = fmaf(Bv.w, u1.w, t);
        uh[c] = t;
    }

    for (int r = 0; r < 3; ++r) {
        // softmax over classes (b_lds -> c_lds); emit c_ij on last iter
        if (tid < NCAPS) {
            int c = tid;
            float x0 = b_lds[c * 4 + 0];
            float x1 = b_lds[c * 4 + 1];
            float x2 = b_lds[c * 4 + 2];
            float x3 = b_lds[c * 4 + 3];
            float m  = fmaxf(fmaxf(x0, x1), fmaxf(x2, x3));
            float e0 = expf(x0 - m), e1 = expf(x1 - m);
            float e2 = expf(x2 - m), e3 = expf(x3 - m);
            float inv = 1.f / (e0 + e1 + e2 + e3);
            e0 *= inv; e1 *= inv; e2 *= inv; e3 *= inv;
            c_lds[c * 4 + 0] = e0;
            c_lds[c * 4 + 1] = e1;
            c_lds[c * 4 + 2] = e2;
            c_lds[c * 4 + 3] = e3;
            if (r == 2) {
                *(float4*)(out + 16384 + ((size_t)b * NCAPS + c) * 4) =
                    make_float4(e0, e1, e2, e3);
            }
        }
        __syncthreads();

        // s_j partial over this wave's 36 capsules
        float partv = 0.f;
#pragma unroll
        for (int c = 0; c < 36; ++c)
            partv = fmaf(c_lds[(g * 36 + c) * 4 + d], uh[c], partv);
        part_lds[tid] = partv;
        __syncthreads();

        if (tid < 64) {
            float sv = 0.f;
#pragma unroll
            for (int k = 0; k < 8; ++k) sv += part_lds[tid + 64 * k];
            float sq = sv * sv;
            sq += __shfl_xor(sq, 1);
            sq += __shfl_xor(sq, 2);
            sq += __shfl_xor(sq, 4);
            sq += __shfl_xor(sq, 8);
            float sc = sq / (1.f + sq) / sqrtf(sq + 1e-8f);
            float v  = sv * sc;
            v_lds[tid] = v;
            if (r == 2) {
                float vv = v * v;
                vv += __shfl_xor(vv, 1);
                vv += __shfl_xor(vv, 2);
                vv += __shfl_xor(vv, 4);
                vv += __shfl_xor(vv, 8);
                if ((tid & 15) == 0)
                    out[(size_t)b * 4 + (tid >> 4)] = sqrtf(vv);
            }
        }
        __syncthreads();

        if (r < 2) {
            float vv = v_lds[l];
#pragma unroll
            for (int c = 0; c < 36; ++c) {
                float t = uh[c] * vv;
                t += __shfl_xor(t, 1);
                t += __shfl_xor(t, 2);
                t += __shfl_xor(t, 4);
                t += __shfl_xor(t, 8);
                if (o == 0) b_lds[(g * 36 + c) * 4 + d] += t;
            }
            __syncthreads();
        }
    }
}

extern "C" void kernel_launch(void* const* d_in, const int* in_sizes, int n_in,
                              void* d_out, int out_size, void* d_ws, size_t ws_size,
                              hipStream_t stream) {
    const float* x      = (const float*)d_in[0];
    const float* a      = (const float*)d_in[1];
    const float* w      = (const float*)d_in[2];
    const float* conv_w = (const float*)d_in[3];
    const float* conv_b = (const float*)d_in[4];
    const float* W_caps = (const float*)d_in[5];
    float* out = (float*)d_out;
    char* ws   = (char*)d_ws;

    float*           w8   = (float*)(ws + W8_OFF);
    __hip_bfloat16*  bph  = (__hip_bfloat16*)(ws + BPH_OFF);
    __hip_bfloat16*  bpl  = (__hip_bfloat16*)(ws + BPL_OFF);
    __hip_bfloat16*  h2hi = (__hip_bfloat16*)(ws + H2HI_OFF);
    __hip_bfloat16*  h2lo = (__hip_bfloat16*)(ws + H2LO_OFF);
    float*           u    = (float*)(ws + U_OFF);

    k_wavelet<<<256, 256, 0, stream>>>(a, w, w8);
    k_pack_b<<<2048, 256, 0, stream>>>(conv_w, bph, bpl);
    k_wavconv<<<BATCH, 256, 0, stream>>>(x, w8, h2hi, h2lo);
    k_conv_mfma<<<BATCH / 16, 512, 0, stream>>>(h2hi, h2lo, bph, bpl, conv_b, u);
    k_routing<<<BATCH, 512, 0, stream>>>(u, W_caps, out);
}

// Round 5
// 462.375 us; speedup vs baseline: 9.1864x; 2.1474x over previous
//
#include <hip/hip_runtime.h>
#include <hip/hip_bf16.h>
#include <math.h>

typedef __attribute__((ext_vector_type(4))) short short4v;
typedef __attribute__((ext_vector_type(8))) short short8;
typedef __attribute__((ext_vector_type(4))) float f32x4;

#define BATCH   4096
#define XLEN    1008
#define NOC1    128
#define NPOS    32
#define NOC2    256
#define NQ      9
#define NCAPS   288
#define NDIM    8

// ws layout (bytes)
#define BWH_OFF   0           // wavelet B-pack hi bf16, 128 KB
#define BWL_OFF   131072      // wavelet B-pack lo bf16, 128 KB
#define BPH_OFF   262144      // conv2 B-pack hi bf16, 1 MB
#define BPL_OFF   1310720     // conv2 B-pack lo bf16, 1 MB
#define H2HI_OFF  2359296     // h2 hi bf16 [b][pos32][ic128], 33.55 MB
#define H2LO_OFF  35913728    // h2 lo bf16, 33.55 MB
#define U_OFF     69468160    // u fp32 [b][288][8], 37.75 MB

struct HL { short hi, lo; };

static __device__ inline HL split2(float v) {
    HL r;
    __hip_bfloat16 h = __float2bfloat16(v);
    r.hi = *reinterpret_cast<short*>(&h);
    float rem = v - __bfloat162float(h);
    __hip_bfloat16 l = __float2bfloat16(rem);
    r.lo = *reinterpret_cast<short*>(&l);
    return r;
}

// ---------------- K1a: wavelet weights directly in MFMA B-fragment order ---
// bwh/bwl[nt 0..7][s 0..15][lane 0..63][e 0..7]:
//   oc = nt*16 + (lane&15), k = s*32 + (lane>>4)*8 + e
__global__ __launch_bounds__(256) void k_wav_pack(const float* __restrict__ a,
                                                  const float* __restrict__ w,
                                                  __hip_bfloat16* __restrict__ bh,
                                                  __hip_bfloat16* __restrict__ bl) {
    int idx = blockIdx.x * 256 + threadIdx.x;   // 65536 total
    int e    = idx & 7;
    int lane = (idx >> 3) & 63;
    int s    = (idx >> 9) & 15;
    int nt   = idx >> 13;
    int oc = nt * 16 + (lane & 15);
    int k  = s * 32 + (lane >> 4) * 8 + e;
    float t  = -1.0f + 2.0f * (float)k / 511.0f;
    float av = fmaxf(a[oc], 1e-5f);
    float ts = t / av;
    float v = cosf(w[oc] * t) * expf(-0.5f * ts * ts);
    HL r = split2(v);
    ((short*)bh)[idx] = r.hi;
    ((short*)bl)[idx] = r.lo;
}

// ---------------- K1b: pack conv_w into MFMA B-fragment order, bf16 hi/lo --
__global__ __launch_bounds__(256) void k_pack_b(const float* __restrict__ cw,
                                                __hip_bfloat16* __restrict__ bh,
                                                __hip_bfloat16* __restrict__ bl) {
    int o = blockIdx.x * 256 + threadIdx.x;   // 524288 total
    int e    = o & 7;
    int lane = (o >> 3) & 63;
    int s    = (o >> 9) & 63;
    int nt   = o >> 15;
    int n  = nt * 16 + (lane & 15);
    int j  = lane >> 4;
    int kk = s >> 2;
    int ic = (s & 3) * 32 + j * 8 + e;
    float v = cw[(n * NOC1 + ic) * 16 + kk];
    HL r = split2(v);
    ((short*)bh)[o] = r.hi;
    ((short*)bl)[o] = r.lo;
}

// ---------------- K2: WavConv via bf16 MFMA (3-term split) -----------------
// Block: 8 batches, 256 threads (4 waves). Wave w: m-tiles 4w..4w+3
// (batches 2w,2w+1 x pos-halves), all 8 n-tiles (128 oc). K=512 in 16 steps.
// x staged once in LDS (hi/lo bf16, pad 8 elems per 16): no K-loop barriers.
__global__ __launch_bounds__(256, 2) void k_wavconv_mfma(
        const float* __restrict__ x,
        const __hip_bfloat16* __restrict__ bwh,
        const __hip_bfloat16* __restrict__ bwl,
        __hip_bfloat16* __restrict__ h2hi,
        __hip_bfloat16* __restrict__ h2lo) {
    __shared__ short xl[2][8][1512];   // 48384 B; slot(i) = i + 8*(i>>4)

    int tid = threadIdx.x;
    int b0  = blockIdx.x * 8;

    // stage x -> bf16 hi/lo
    for (int i4 = tid; i4 < 2016; i4 += 256) {
        int b  = i4 / 252;
        int e4 = i4 - b * 252;
        float4 v = *(const float4*)(x + (size_t)(b0 + b) * XLEN + e4 * 4);
        int i    = e4 * 4;
        int slot = i + 8 * (i >> 4);
        HL r0 = split2(v.x);
        HL r1 = split2(v.y);
        HL r2 = split2(v.z);
        HL r3 = split2(v.w);
        short4v hv, lv;
        hv.x = r0.hi; hv.y = r1.hi; hv.z = r2.hi; hv.w = r3.hi;
        lv.x = r0.lo; lv.y = r1.lo; lv.z = r2.lo; lv.w = r3.lo;
        *(short4v*)&xl[0][b][slot] = hv;
        *(short4v*)&xl[1][b][slot] = lv;
    }
    __syncthreads();

    int lane = tid & 63;
    int w    = tid >> 6;     // 0..3
    int col  = lane & 15;
    int rg   = lane >> 4;    // 0..3

    f32x4 acc[4][8];
    f32x4 z = {0.f, 0.f, 0.f, 0.f};
#pragma unroll
    for (int tl = 0; tl < 4; ++tl)
#pragma unroll
        for (int nt = 0; nt < 8; ++nt) acc[tl][nt] = z;

    for (int s = 0; s < 16; ++s) {
        short8 Bh[8], Bl[8];
#pragma unroll
        for (int nt = 0; nt < 8; ++nt) {
            size_t off = ((size_t)(nt * 16 + s) * 64 + lane) * 8;
            Bh[nt] = *(const short8*)(bwh + off);
            Bl[nt] = *(const short8*)(bwl + off);
        }
#pragma unroll
        for (int tl = 0; tl < 4; ++tl) {
            int mt  = 4 * w + tl;
            int bl  = mt >> 1;                  // block-local batch
            int pos = (mt & 1) * 16 + col;
            int i    = (pos + 2 * s) * 16 + rg * 8;
            int slot = i + 8 * (i >> 4);
            short8 ah = *(const short8*)&xl[0][bl][slot];
            short8 al = *(const short8*)&xl[1][bl][slot];
#pragma unroll
            for (int nt = 0; nt < 8; ++nt) {
                acc[tl][nt] = __builtin_amdgcn_mfma_f32_16x16x32_bf16(ah, Bh[nt], acc[tl][nt], 0, 0, 0);
                acc[tl][nt] = __builtin_amdgcn_mfma_f32_16x16x32_bf16(ah, Bl[nt], acc[tl][nt], 0, 0, 0);
                acc[tl][nt] = __builtin_amdgcn_mfma_f32_16x16x32_bf16(al, Bh[nt], acc[tl][nt], 0, 0, 0);
            }
        }
    }

    // Epilogue: C/D layout col=lane&15 (oc within tile), row=rg*4+r (pos).
#pragma unroll
    for (int tl = 0; tl < 4; ++tl) {
        int mt = 4 * w + tl;
        int b  = b0 + (mt >> 1);
        int ph = (mt & 1) * 16;
#pragma unroll
        for (int nt = 0; nt < 8; ++nt) {
            int oc = nt * 16 + col;
#pragma unroll
            for (int r = 0; r < 4; ++r) {
                int pos = ph + rg * 4 + r;
                size_t off = ((size_t)b * NPOS + pos) * NOC1 + oc;
                HL rr = split2(acc[tl][nt][r]);
                ((short*)h2hi)[off] = rr.hi;
                ((short*)h2lo)[off] = rr.lo;
            }
        }
    }
}

// ---------------- K3: PrimaryCaps conv via bf16 MFMA (3-term split) + squash
__global__ __launch_bounds__(512) void k_conv_mfma(const __hip_bfloat16* __restrict__ h2hi,
                                                   const __hip_bfloat16* __restrict__ h2lo,
                                                   const __hip_bfloat16* __restrict__ bph,
                                                   const __hip_bfloat16* __restrict__ bpl,
                                                   const float* __restrict__ cb,
                                                   float* __restrict__ u) {
    __shared__ float smem[18432];            // 73728 B: A-staging, then p-exchange
    short* Alds  = (short*)smem;             // [2 variants][144 m][stride 40]
    float* p_lds = smem;                     // [16 b][1152]

    int tid  = threadIdx.x;
    int w    = tid >> 6;
    int lane = tid & 63;
    int col  = lane & 15;
    int rg   = lane >> 4;
    int b0   = blockIdx.x * 16;

    f32x4 acc0[9], acc1[9];
    f32x4 z = {0.f, 0.f, 0.f, 0.f};
#pragma unroll
    for (int mt = 0; mt < 9; ++mt) { acc0[mt] = z; acc1[mt] = z; }

    for (int s = 0; s < 64; ++s) {
        int kk  = s >> 2;
        int icb = (s & 3) * 32;
        __syncthreads();
        for (int idx = tid; idx < 1152; idx += 512) {
            int v  = idx >= 576;
            int j2 = idx - v * 576;
            int m  = j2 >> 2;
            int g  = j2 & 3;
            const __hip_bfloat16* src = (v ? h2lo : h2hi) +
                ((size_t)(b0 + (m & 15)) * NPOS + (2 * (m >> 4) + kk)) * NOC1 + icb + g * 8;
            short8 val = *(const short8*)src;
            *(short8*)&Alds[v * 5760 + m * 40 + g * 8] = val;
        }
        __syncthreads();

        size_t bo0 = ((size_t)(w * 64 + s) * 64 + lane) * 8;
        size_t bo1 = ((size_t)((8 + w) * 64 + s) * 64 + lane) * 8;
        short8 b0h = *(const short8*)(bph + bo0);
        short8 b0l = *(const short8*)(bpl + bo0);
        short8 b1h = *(const short8*)(bph + bo1);
        short8 b1l = *(const short8*)(bpl + bo1);

#pragma unroll
        for (int mt = 0; mt < 9; ++mt) {
            int aoff = (mt * 16 + col) * 40 + rg * 8;
            short8 ah = *(const short8*)&Alds[aoff];
            short8 al = *(const short8*)&Alds[5760 + aoff];
            acc0[mt] = __builtin_amdgcn_mfma_f32_16x16x32_bf16(ah, b0h, acc0[mt], 0, 0, 0);
            acc0[mt] = __builtin_amdgcn_mfma_f32_16x16x32_bf16(ah, b0l, acc0[mt], 0, 0, 0);
            acc0[mt] = __builtin_amdgcn_mfma_f32_16x16x32_bf16(al, b0h, acc0[mt], 0, 0, 0);
            acc1[mt] = __builtin_amdgcn_mfma_f32_16x16x32_bf16(ah, b1h, acc1[mt], 0, 0, 0);
            acc1[mt] = __builtin_amdgcn_mfma_f32_16x16x32_bf16(ah, b1l, acc1[mt], 0, 0, 0);
            acc1[mt] = __builtin_amdgcn_mfma_f32_16x16x32_bf16(al, b1h, acc1[mt], 0, 0, 0);
        }
    }
    __syncthreads();

    for (int ch = 0; ch < 2; ++ch) {
        int oc2l = w * 16 + col;
        float bias = cb[ch * 128 + oc2l];
        f32x4* accp = ch ? acc1 : acc0;
#pragma unroll
        for (int mt = 0; mt < 9; ++mt)
#pragma unroll
            for (int r = 0; r < 4; ++r) {
                int b = rg * 4 + r;
                p_lds[b * 1152 + oc2l * 9 + mt] = accp[mt][r] + bias;
            }
        __syncthreads();
        for (int idx = tid; idx < 2304; idx += 512) {
            int b  = idx / 144;
            int cl = idx - b * 144;
            float* pp = &p_lds[b * 1152 + cl * 8];
            float sn = 0.f;
#pragma unroll
            for (int i = 0; i < NDIM; ++i) sn = fmaf(pp[i], pp[i], sn);
            float sc = sn / (1.f + sn) / sqrtf(sn + 1e-8f);
            float* ug = u + ((size_t)(b0 + b) * (NCAPS * NDIM) + (ch * 144 + cl) * 8);
            float4 u0 = make_float4(pp[0] * sc, pp[1] * sc, pp[2] * sc, pp[3] * sc);
            float4 u1 = make_float4(pp[4] * sc, pp[5] * sc, pp[6] * sc, pp[7] * sc);
            ((float4*)ug)[0] = u0;
            ((float4*)ug)[1] = u1;
        }
        __syncthreads();
    }
}

// ---------------- K4: u_hat + dynamic routing, 1 batch/block, 512 threads --
__global__ __launch_bounds__(512, 4) void k_routing(const float* __restrict__ u,
                                                    const float* __restrict__ Wc,
                                                    float* __restrict__ out) {
    __shared__ float u_lds[NCAPS * NDIM];   // 9216 B
    __shared__ float b_lds[NCAPS * 4];      // 4608 B
    __shared__ float c_lds[NCAPS * 4];      // 4608 B
    __shared__ float part_lds[512];         // 2048 B
    __shared__ float v_lds[64];             // 256 B

    int tid = threadIdx.x;
    int b   = blockIdx.x;

    {
        const float4* ug = (const float4*)(u + (size_t)b * (NCAPS * NDIM));
        float4* ul = (float4*)u_lds;
        for (int i = tid; i < NCAPS * NDIM / 4; i += 512) ul[i] = ug[i];
    }
    for (int i = tid; i < NCAPS * 4; i += 512) b_lds[i] = 0.f;
    __syncthreads();

    int g = tid >> 6;
    int l = tid & 63;
    int d = l >> 4;
    int o = l & 15;

    float uh[36];
#pragma unroll
    for (int c = 0; c < 36; ++c) {
        int cap = g * 36 + c;
        const float4* W4 = (const float4*)(Wc + ((size_t)cap * 512) + l * 8);
        float4 A  = W4[0];
        float4 Bv = W4[1];
        const float4* uu = (const float4*)(u_lds + cap * NDIM);
        float4 u0 = uu[0], u1 = uu[1];
        float t = A.x * u0.x;
        t = fmaf(A.y,  u0.y, t);
        t = fmaf(A.z,  u0.z, t);
        t = fmaf(A.w,  u0.w, t);
        t = fmaf(Bv.x, u1.x, t);
        t = fmaf(Bv.y, u1.y, t);
        t = fmaf(Bv.z, u1.z, t);
        t = fmaf(Bv.w, u1.w, t);
        uh[c] = t;
    }

    for (int r = 0; r < 3; ++r) {
        if (tid < NCAPS) {
            int c = tid;
            float x0 = b_lds[c * 4 + 0];
            float x1 = b_lds[c * 4 + 1];
            float x2 = b_lds[c * 4 + 2];
            float x3 = b_lds[c * 4 + 3];
            float m  = fmaxf(fmaxf(x0, x1), fmaxf(x2, x3));
            float e0 = expf(x0 - m), e1 = expf(x1 - m);
            float e2 = expf(x2 - m), e3 = expf(x3 - m);
            float inv = 1.f / (e0 + e1 + e2 + e3);
            e0 *= inv; e1 *= inv; e2 *= inv; e3 *= inv;
            c_lds[c * 4 + 0] = e0;
            c_lds[c * 4 + 1] = e1;
            c_lds[c * 4 + 2] = e2;
            c_lds[c * 4 + 3] = e3;
            if (r == 2) {
                *(float4*)(out + 16384 + ((size_t)b * NCAPS + c) * 4) =
                    make_float4(e0, e1, e2, e3);
            }
        }
        __syncthreads();

        float partv = 0.f;
#pragma unroll
        for (int c = 0; c < 36; ++c)
            partv = fmaf(c_lds[(g * 36 + c) * 4 + d], uh[c], partv);
        part_lds[tid] = partv;
        __syncthreads();

        if (tid < 64) {
            float sv = 0.f;
#pragma unroll
            for (int k = 0; k < 8; ++k) sv += part_lds[tid + 64 * k];
            float sq = sv * sv;
            sq += __shfl_xor(sq, 1);
            sq += __shfl_xor(sq, 2);
            sq += __shfl_xor(sq, 4);
            sq += __shfl_xor(sq, 8);
            float sc = sq / (1.f + sq) / sqrtf(sq + 1e-8f);
            float v  = sv * sc;
            v_lds[tid] = v;
            if (r == 2) {
                float vv = v * v;
                vv += __shfl_xor(vv, 1);
                vv += __shfl_xor(vv, 2);
                vv += __shfl_xor(vv, 4);
                vv += __shfl_xor(vv, 8);
                if ((tid & 15) == 0)
                    out[(size_t)b * 4 + (tid >> 4)] = sqrtf(vv);
            }
        }
        __syncthreads();

        if (r < 2) {
            float vv = v_lds[l];
#pragma unroll
            for (int c = 0; c < 36; ++c) {
                float t = uh[c] * vv;
                t += __shfl_xor(t, 1);
                t += __shfl_xor(t, 2);
                t += __shfl_xor(t, 4);
                t += __shfl_xor(t, 8);
                if (o == 0) b_lds[(g * 36 + c) * 4 + d] += t;
            }
            __syncthreads();
        }
    }
}

extern "C" void kernel_launch(void* const* d_in, const int* in_sizes, int n_in,
                              void* d_out, int out_size, void* d_ws, size_t ws_size,
                              hipStream_t stream) {
    const float* x      = (const float*)d_in[0];
    const float* a      = (const float*)d_in[1];
    const float* w      = (const float*)d_in[2];
    const float* conv_w = (const float*)d_in[3];
    const float* conv_b = (const float*)d_in[4];
    const float* W_caps = (const float*)d_in[5];
    float* out = (float*)d_out;
    char* ws   = (char*)d_ws;

    __hip_bfloat16*  bwh  = (__hip_bfloat16*)(ws + BWH_OFF);
    __hip_bfloat16*  bwl  = (__hip_bfloat16*)(ws + BWL_OFF);
    __hip_bfloat16*  bph  = (__hip_bfloat16*)(ws + BPH_OFF);
    __hip_bfloat16*  bpl  = (__hip_bfloat16*)(ws + BPL_OFF);
    __hip_bfloat16*  h2hi = (__hip_bfloat16*)(ws + H2HI_OFF);
    __hip_bfloat16*  h2lo = (__hip_bfloat16*)(ws + H2LO_OFF);
    float*           u    = (float*)(ws + U_OFF);

    k_wav_pack<<<256, 256, 0, stream>>>(a, w, bwh, bwl);
    k_pack_b<<<2048, 256, 0, stream>>>(conv_w, bph, bpl);
    k_wavconv_mfma<<<BATCH / 8, 256, 0, stream>>>(x, bwh, bwl, h2hi, h2lo);
    k_conv_mfma<<<BATCH / 16, 512, 0, stream>>>(h2hi, h2lo, bph, bpl, conv_b, u);
    k_routing<<<BATCH, 512, 0, stream>>>(u, W_caps, out);
}

// Round 6
// 423.738 us; speedup vs baseline: 10.0240x; 1.0912x over previous
//
#include <hip/hip_runtime.h>
#include <hip/hip_bf16.h>
#include <math.h>

typedef __attribute__((ext_vector_type(4))) short short4v;
typedef __attribute__((ext_vector_type(8))) short short8;
typedef __attribute__((ext_vector_type(4))) float f32x4;

#define BATCH   4096
#define XLEN    1008
#define NOC1    128
#define NPOS    32
#define NOC2    256
#define NQ      9
#define NCAPS   288
#define NDIM    8

// ws layout (bytes)
#define BWH_OFF   0           // wavelet B-pack hi bf16, 128 KB
#define BWL_OFF   131072      // wavelet B-pack lo bf16, 128 KB
#define BPH_OFF   262144      // conv2 B-pack hi bf16, 1 MB
#define BPL_OFF   1310720     // conv2 B-pack lo bf16, 1 MB
#define H2HI_OFF  2359296     // h2 hi bf16 [b][pos32][ic128], 33.55 MB
#define H2LO_OFF  35913728    // h2 lo bf16, 33.55 MB
#define U_OFF     69468160    // u fp32 [b][288][8], 37.75 MB

struct HL { short hi, lo; };

static __device__ inline HL split2(float v) {
    HL r;
    __hip_bfloat16 h = __float2bfloat16(v);
    r.hi = *reinterpret_cast<short*>(&h);
    float rem = v - __bfloat162float(h);
    __hip_bfloat16 l = __float2bfloat16(rem);
    r.lo = *reinterpret_cast<short*>(&l);
    return r;
}

// ---------------- K1a: wavelet weights directly in MFMA B-fragment order ---
__global__ __launch_bounds__(256) void k_wav_pack(const float* __restrict__ a,
                                                  const float* __restrict__ w,
                                                  __hip_bfloat16* __restrict__ bh,
                                                  __hip_bfloat16* __restrict__ bl) {
    int idx = blockIdx.x * 256 + threadIdx.x;   // 65536 total
    int e    = idx & 7;
    int lane = (idx >> 3) & 63;
    int s    = (idx >> 9) & 15;
    int nt   = idx >> 13;
    int oc = nt * 16 + (lane & 15);
    int k  = s * 32 + (lane >> 4) * 8 + e;
    float t  = -1.0f + 2.0f * (float)k / 511.0f;
    float av = fmaxf(a[oc], 1e-5f);
    float ts = t / av;
    float v = cosf(w[oc] * t) * expf(-0.5f * ts * ts);
    HL r = split2(v);
    ((short*)bh)[idx] = r.hi;
    ((short*)bl)[idx] = r.lo;
}

// ---------------- K1b: pack conv_w into MFMA B-fragment order, bf16 hi/lo --
__global__ __launch_bounds__(256) void k_pack_b(const float* __restrict__ cw,
                                                __hip_bfloat16* __restrict__ bh,
                                                __hip_bfloat16* __restrict__ bl) {
    int o = blockIdx.x * 256 + threadIdx.x;   // 524288 total
    int e    = o & 7;
    int lane = (o >> 3) & 63;
    int s    = (o >> 9) & 63;
    int nt   = o >> 15;
    int n  = nt * 16 + (lane & 15);
    int j  = lane >> 4;
    int kk = s >> 2;
    int ic = (s & 3) * 32 + j * 8 + e;
    float v = cw[(n * NOC1 + ic) * 16 + kk];
    HL r = split2(v);
    ((short*)bh)[o] = r.hi;
    ((short*)bl)[o] = r.lo;
}

// ---------------- K2: WavConv via bf16 MFMA (3-term split) -----------------
__global__ __launch_bounds__(256, 2) void k_wavconv_mfma(
        const float* __restrict__ x,
        const __hip_bfloat16* __restrict__ bwh,
        const __hip_bfloat16* __restrict__ bwl,
        __hip_bfloat16* __restrict__ h2hi,
        __hip_bfloat16* __restrict__ h2lo) {
    __shared__ short xl[2][8][1512];   // 48384 B; slot(i) = i + 8*(i>>4)

    int tid = threadIdx.x;
    int b0  = blockIdx.x * 8;

    for (int i4 = tid; i4 < 2016; i4 += 256) {
        int b  = i4 / 252;
        int e4 = i4 - b * 252;
        float4 v = *(const float4*)(x + (size_t)(b0 + b) * XLEN + e4 * 4);
        int i    = e4 * 4;
        int slot = i + 8 * (i >> 4);
        HL r0 = split2(v.x);
        HL r1 = split2(v.y);
        HL r2 = split2(v.z);
        HL r3 = split2(v.w);
        short4v hv, lv;
        hv.x = r0.hi; hv.y = r1.hi; hv.z = r2.hi; hv.w = r3.hi;
        lv.x = r0.lo; lv.y = r1.lo; lv.z = r2.lo; lv.w = r3.lo;
        *(short4v*)&xl[0][b][slot] = hv;
        *(short4v*)&xl[1][b][slot] = lv;
    }
    __syncthreads();

    int lane = tid & 63;
    int w    = tid >> 6;     // 0..3
    int col  = lane & 15;
    int rg   = lane >> 4;    // 0..3

    f32x4 acc[4][8];
    f32x4 z = {0.f, 0.f, 0.f, 0.f};
#pragma unroll
    for (int tl = 0; tl < 4; ++tl)
#pragma unroll
        for (int nt = 0; nt < 8; ++nt) acc[tl][nt] = z;

    for (int s = 0; s < 16; ++s) {
        short8 Bh[8], Bl[8];
#pragma unroll
        for (int nt = 0; nt < 8; ++nt) {
            size_t off = ((size_t)(nt * 16 + s) * 64 + lane) * 8;
            Bh[nt] = *(const short8*)(bwh + off);
            Bl[nt] = *(const short8*)(bwl + off);
        }
#pragma unroll
        for (int tl = 0; tl < 4; ++tl) {
            int mt  = 4 * w + tl;
            int bl  = mt >> 1;
            int pos = (mt & 1) * 16 + col;
            int i    = (pos + 2 * s) * 16 + rg * 8;
            int slot = i + 8 * (i >> 4);
            short8 ah = *(const short8*)&xl[0][bl][slot];
            short8 al = *(const short8*)&xl[1][bl][slot];
#pragma unroll
            for (int nt = 0; nt < 8; ++nt) {
                acc[tl][nt] = __builtin_amdgcn_mfma_f32_16x16x32_bf16(ah, Bh[nt], acc[tl][nt], 0, 0, 0);
                acc[tl][nt] = __builtin_amdgcn_mfma_f32_16x16x32_bf16(ah, Bl[nt], acc[tl][nt], 0, 0, 0);
                acc[tl][nt] = __builtin_amdgcn_mfma_f32_16x16x32_bf16(al, Bh[nt], acc[tl][nt], 0, 0, 0);
            }
        }
    }

#pragma unroll
    for (int tl = 0; tl < 4; ++tl) {
        int mt = 4 * w + tl;
        int b  = b0 + (mt >> 1);
        int ph = (mt & 1) * 16;
#pragma unroll
        for (int nt = 0; nt < 8; ++nt) {
            int oc = nt * 16 + col;
#pragma unroll
            for (int r = 0; r < 4; ++r) {
                int pos = ph + rg * 4 + r;
                size_t off = ((size_t)b * NPOS + pos) * NOC1 + oc;
                HL rr = split2(acc[tl][nt][r]);
                ((short*)h2hi)[off] = rr.hi;
                ((short*)h2lo)[off] = rr.lo;
            }
        }
    }
}

// ---------------- K3: PrimaryCaps conv via bf16 MFMA (3-term split) + squash
__global__ __launch_bounds__(512) void k_conv_mfma(const __hip_bfloat16* __restrict__ h2hi,
                                                   const __hip_bfloat16* __restrict__ h2lo,
                                                   const __hip_bfloat16* __restrict__ bph,
                                                   const __hip_bfloat16* __restrict__ bpl,
                                                   const float* __restrict__ cb,
                                                   float* __restrict__ u) {
    __shared__ float smem[18432];            // 73728 B: A-staging, then p-exchange
    short* Alds  = (short*)smem;             // [2 variants][144 m][stride 40]
    float* p_lds = smem;                     // [16 b][1152]

    int tid  = threadIdx.x;
    int w    = tid >> 6;
    int lane = tid & 63;
    int col  = lane & 15;
    int rg   = lane >> 4;
    int b0   = blockIdx.x * 16;

    f32x4 acc0[9], acc1[9];
    f32x4 z = {0.f, 0.f, 0.f, 0.f};
#pragma unroll
    for (int mt = 0; mt < 9; ++mt) { acc0[mt] = z; acc1[mt] = z; }

    for (int s = 0; s < 64; ++s) {
        int kk  = s >> 2;
        int icb = (s & 3) * 32;
        __syncthreads();
        for (int idx = tid; idx < 1152; idx += 512) {
            int v  = idx >= 576;
            int j2 = idx - v * 576;
            int m  = j2 >> 2;
            int g  = j2 & 3;
            const __hip_bfloat16* src = (v ? h2lo : h2hi) +
                ((size_t)(b0 + (m & 15)) * NPOS + (2 * (m >> 4) + kk)) * NOC1 + icb + g * 8;
            short8 val = *(const short8*)src;
            *(short8*)&Alds[v * 5760 + m * 40 + g * 8] = val;
        }
        __syncthreads();

        size_t bo0 = ((size_t)(w * 64 + s) * 64 + lane) * 8;
        size_t bo1 = ((size_t)((8 + w) * 64 + s) * 64 + lane) * 8;
        short8 b0h = *(const short8*)(bph + bo0);
        short8 b0l = *(const short8*)(bpl + bo0);
        short8 b1h = *(const short8*)(bph + bo1);
        short8 b1l = *(const short8*)(bpl + bo1);

#pragma unroll
        for (int mt = 0; mt < 9; ++mt) {
            int aoff = (mt * 16 + col) * 40 + rg * 8;
            short8 ah = *(const short8*)&Alds[aoff];
            short8 al = *(const short8*)&Alds[5760 + aoff];
            acc0[mt] = __builtin_amdgcn_mfma_f32_16x16x32_bf16(ah, b0h, acc0[mt], 0, 0, 0);
            acc0[mt] = __builtin_amdgcn_mfma_f32_16x16x32_bf16(ah, b0l, acc0[mt], 0, 0, 0);
            acc0[mt] = __builtin_amdgcn_mfma_f32_16x16x32_bf16(al, b0h, acc0[mt], 0, 0, 0);
            acc1[mt] = __builtin_amdgcn_mfma_f32_16x16x32_bf16(ah, b1h, acc1[mt], 0, 0, 0);
            acc1[mt] = __builtin_amdgcn_mfma_f32_16x16x32_bf16(ah, b1l, acc1[mt], 0, 0, 0);
            acc1[mt] = __builtin_amdgcn_mfma_f32_16x16x32_bf16(al, b1h, acc1[mt], 0, 0, 0);
        }
    }
    __syncthreads();

    for (int ch = 0; ch < 2; ++ch) {
        int oc2l = w * 16 + col;
        float bias = cb[ch * 128 + oc2l];
        f32x4* accp = ch ? acc1 : acc0;
#pragma unroll
        for (int mt = 0; mt < 9; ++mt)
#pragma unroll
            for (int r = 0; r < 4; ++r) {
                int b = rg * 4 + r;
                p_lds[b * 1152 + oc2l * 9 + mt] = accp[mt][r] + bias;
            }
        __syncthreads();
        for (int idx = tid; idx < 2304; idx += 512) {
            int b  = idx / 144;
            int cl = idx - b * 144;
            float* pp = &p_lds[b * 1152 + cl * 8];
            float sn = 0.f;
#pragma unroll
            for (int i = 0; i < NDIM; ++i) sn = fmaf(pp[i], pp[i], sn);
            float sc = sn / (1.f + sn) / sqrtf(sn + 1e-8f);
            float* ug = u + ((size_t)(b0 + b) * (NCAPS * NDIM) + (ch * 144 + cl) * 8);
            float4 u0 = make_float4(pp[0] * sc, pp[1] * sc, pp[2] * sc, pp[3] * sc);
            float4 u1 = make_float4(pp[4] * sc, pp[5] * sc, pp[6] * sc, pp[7] * sc);
            ((float4*)ug)[0] = u0;
            ((float4*)ug)[1] = u1;
        }
        __syncthreads();
    }
}

// ---------------- K4: u_hat + dynamic routing, 2 batches/block, 512 threads
// 8 waves; wave g owns capsules [g*36, g*36+36). lane l -> (d = l>>4, o = l&15).
// u is read via wave-uniform (scalar) loads straight from global.
__global__ __launch_bounds__(512, 4) void k_routing(const float* __restrict__ u,
                                                    const float* __restrict__ Wc,
                                                    float* __restrict__ out) {
    __shared__ float b_lds[2][NCAPS * 4];     // 9216 B
    __shared__ float c_lds[2][NCAPS * 4];     // 9216 B
    __shared__ float part_lds[2][512];        // 4096 B
    __shared__ float v_lds[2][64];            // 512 B

    int tid = threadIdx.x;
    int b0  = blockIdx.x * 2;

    for (int i = tid; i < 2 * NCAPS * 4; i += 512) ((float*)b_lds)[i] = 0.f;

    int g = tid >> 6;
    int l = tid & 63;
    int d = l >> 4;
    int o = l & 15;
    int gu = __builtin_amdgcn_readfirstlane(g);   // force wave-uniform -> s_load for u

    const float* ub0 = u + (size_t)(b0 + 0) * (NCAPS * NDIM) + gu * 36 * NDIM;
    const float* ub1 = u + (size_t)(b0 + 1) * (NCAPS * NDIM) + gu * 36 * NDIM;

    float uh0[36], uh1[36];
#pragma unroll
    for (int c = 0; c < 36; ++c) {
        int cap = gu * 36 + c;
        const float4* W4 = (const float4*)(Wc + ((size_t)cap * 512) + l * 8);
        float4 A  = W4[0];
        float4 Bv = W4[1];
        float t0 = A.x * ub0[c * 8 + 0];
        t0 = fmaf(A.y,  ub0[c * 8 + 1], t0);
        t0 = fmaf(A.z,  ub0[c * 8 + 2], t0);
        t0 = fmaf(A.w,  ub0[c * 8 + 3], t0);
        t0 = fmaf(Bv.x, ub0[c * 8 + 4], t0);
        t0 = fmaf(Bv.y, ub0[c * 8 + 5], t0);
        t0 = fmaf(Bv.z, ub0[c * 8 + 6], t0);
        t0 = fmaf(Bv.w, ub0[c * 8 + 7], t0);
        uh0[c] = t0;
        float t1 = A.x * ub1[c * 8 + 0];
        t1 = fmaf(A.y,  ub1[c * 8 + 1], t1);
        t1 = fmaf(A.z,  ub1[c * 8 + 2], t1);
        t1 = fmaf(A.w,  ub1[c * 8 + 3], t1);
        t1 = fmaf(Bv.x, ub1[c * 8 + 4], t1);
        t1 = fmaf(Bv.y, ub1[c * 8 + 5], t1);
        t1 = fmaf(Bv.z, ub1[c * 8 + 6], t1);
        t1 = fmaf(Bv.w, ub1[c * 8 + 7], t1);
        uh1[c] = t1;
    }
    __syncthreads();

    for (int r = 0; r < 3; ++r) {
        // softmax over classes for both batches (576 caps total)
        for (int idx = tid; idx < 2 * NCAPS; idx += 512) {
            int bb = idx >= NCAPS;
            int c  = idx - bb * NCAPS;
            float x0 = b_lds[bb][c * 4 + 0];
            float x1 = b_lds[bb][c * 4 + 1];
            float x2 = b_lds[bb][c * 4 + 2];
            float x3 = b_lds[bb][c * 4 + 3];
            float m  = fmaxf(fmaxf(x0, x1), fmaxf(x2, x3));
            float e0 = expf(x0 - m), e1 = expf(x1 - m);
            float e2 = expf(x2 - m), e3 = expf(x3 - m);
            float inv = 1.f / (e0 + e1 + e2 + e3);
            e0 *= inv; e1 *= inv; e2 *= inv; e3 *= inv;
            c_lds[bb][c * 4 + 0] = e0;
            c_lds[bb][c * 4 + 1] = e1;
            c_lds[bb][c * 4 + 2] = e2;
            c_lds[bb][c * 4 + 3] = e3;
            if (r == 2) {
                *(float4*)(out + 16384 + ((size_t)(b0 + bb) * NCAPS + c) * 4) =
                    make_float4(e0, e1, e2, e3);
            }
        }
        __syncthreads();

        // s_j partials over this wave's 36 capsules, both batches
        float p0 = 0.f, p1 = 0.f;
#pragma unroll
        for (int c = 0; c < 36; ++c) {
            p0 = fmaf(c_lds[0][(g * 36 + c) * 4 + d], uh0[c], p0);
            p1 = fmaf(c_lds[1][(g * 36 + c) * 4 + d], uh1[c], p1);
        }
        part_lds[0][tid] = p0;
        part_lds[1][tid] = p1;
        __syncthreads();

        if (tid < 128) {
            int bb = tid >> 6;
            int ll = tid & 63;
            float sv = 0.f;
#pragma unroll
            for (int k = 0; k < 8; ++k) sv += part_lds[bb][ll + 64 * k];
            float sq = sv * sv;
            sq += __shfl_xor(sq, 1);
            sq += __shfl_xor(sq, 2);
            sq += __shfl_xor(sq, 4);
            sq += __shfl_xor(sq, 8);
            float sc = sq / (1.f + sq) / sqrtf(sq + 1e-8f);
            float v  = sv * sc;
            v_lds[bb][ll] = v;
            if (r == 2) {
                float vv = v * v;
                vv += __shfl_xor(vv, 1);
                vv += __shfl_xor(vv, 2);
                vv += __shfl_xor(vv, 4);
                vv += __shfl_xor(vv, 8);
                if ((ll & 15) == 0)
                    out[(size_t)(b0 + bb) * 4 + (ll >> 4)] = sqrtf(vv);
            }
        }
        __syncthreads();

        if (r < 2) {
            float v0 = v_lds[0][l];
            float v1 = v_lds[1][l];
#pragma unroll
            for (int c = 0; c < 36; ++c) {
                float t0 = uh0[c] * v0;
                t0 += __shfl_xor(t0, 1);
                t0 += __shfl_xor(t0, 2);
                t0 += __shfl_xor(t0, 4);
                t0 += __shfl_xor(t0, 8);
                float t1 = uh1[c] * v1;
                t1 += __shfl_xor(t1, 1);
                t1 += __shfl_xor(t1, 2);
                t1 += __shfl_xor(t1, 4);
                t1 += __shfl_xor(t1, 8);
                if (o == 0) {
                    b_lds[0][(g * 36 + c) * 4 + d] += t0;
                    b_lds[1][(g * 36 + c) * 4 + d] += t1;
                }
            }
            __syncthreads();
        }
    }
}

extern "C" void kernel_launch(void* const* d_in, const int* in_sizes, int n_in,
                              void* d_out, int out_size, void* d_ws, size_t ws_size,
                              hipStream_t stream) {
    const float* x      = (const float*)d_in[0];
    const float* a      = (const float*)d_in[1];
    const float* w      = (const float*)d_in[2];
    const float* conv_w = (const float*)d_in[3];
    const float* conv_b = (const float*)d_in[4];
    const float* W_caps = (const float*)d_in[5];
    float* out = (float*)d_out;
    char* ws   = (char*)d_ws;

    __hip_bfloat16*  bwh  = (__hip_bfloat16*)(ws + BWH_OFF);
    __hip_bfloat16*  bwl  = (__hip_bfloat16*)(ws + BWL_OFF);
    __hip_bfloat16*  bph  = (__hip_bfloat16*)(ws + BPH_OFF);
    __hip_bfloat16*  bpl  = (__hip_bfloat16*)(ws + BPL_OFF);
    __hip_bfloat16*  h2hi = (__hip_bfloat16*)(ws + H2HI_OFF);
    __hip_bfloat16*  h2lo = (__hip_bfloat16*)(ws + H2LO_OFF);
    float*           u    = (float*)(ws + U_OFF);

    k_wav_pack<<<256, 256, 0, stream>>>(a, w, bwh, bwl);
    k_pack_b<<<2048, 256, 0, stream>>>(conv_w, bph, bpl);
    k_wavconv_mfma<<<BATCH / 8, 256, 0, stream>>>(x, bwh, bwl, h2hi, h2lo);
    k_conv_mfma<<<BATCH / 16, 512, 0, stream>>>(h2hi, h2lo, bph, bpl, conv_b, u);
    k_routing<<<BATCH / 2, 512, 0, stream>>>(u, W_caps, out);
}

// Round 7
// 420.296 us; speedup vs baseline: 10.1061x; 1.0082x over previous
//
#include <hip/hip_runtime.h>
#include <hip/hip_bf16.h>
#include <math.h>

typedef __attribute__((ext_vector_type(4))) short short4v;
typedef __attribute__((ext_vector_type(8))) short short8;
typedef __attribute__((ext_vector_type(4))) float f32x4;

#define BATCH   4096
#define XLEN    1008
#define NOC1    128
#define NPOS    32
#define NOC2    256
#define NQ      9
#define NCAPS   288
#define NDIM    8

// ws layout (bytes)
#define BWH_OFF   0           // wavelet B-pack hi bf16, 128 KB
#define BWL_OFF   131072      // wavelet B-pack lo bf16, 128 KB
#define BPH_OFF   262144      // conv2 B-pack hi bf16, 1 MB
#define BPL_OFF   1310720     // conv2 B-pack lo bf16, 1 MB
#define H2HI_OFF  2359296     // h2 hi bf16 [b][pos32][ic128], 33.55 MB
#define H2LO_OFF  35913728    // h2 lo bf16, 33.55 MB
#define U_OFF     69468160    // u fp32 [b][288][8], 37.75 MB

struct HL { short hi, lo; };

static __device__ inline HL split2(float v) {
    HL r;
    __hip_bfloat16 h = __float2bfloat16(v);
    r.hi = *reinterpret_cast<short*>(&h);
    float rem = v - __bfloat162float(h);
    __hip_bfloat16 l = __float2bfloat16(rem);
    r.lo = *reinterpret_cast<short*>(&l);
    return r;
}

// ---------------- K1a: wavelet weights directly in MFMA B-fragment order ---
__global__ __launch_bounds__(256) void k_wav_pack(const float* __restrict__ a,
                                                  const float* __restrict__ w,
                                                  __hip_bfloat16* __restrict__ bh,
                                                  __hip_bfloat16* __restrict__ bl) {
    int idx = blockIdx.x * 256 + threadIdx.x;   // 65536 total
    int e    = idx & 7;
    int lane = (idx >> 3) & 63;
    int s    = (idx >> 9) & 15;
    int nt   = idx >> 13;
    int oc = nt * 16 + (lane & 15);
    int k  = s * 32 + (lane >> 4) * 8 + e;
    float t  = -1.0f + 2.0f * (float)k / 511.0f;
    float av = fmaxf(a[oc], 1e-5f);
    float ts = t / av;
    float v = cosf(w[oc] * t) * expf(-0.5f * ts * ts);
    HL r = split2(v);
    ((short*)bh)[idx] = r.hi;
    ((short*)bl)[idx] = r.lo;
}

// ---------------- K1b: pack conv_w into MFMA B-fragment order, bf16 hi/lo --
__global__ __launch_bounds__(256) void k_pack_b(const float* __restrict__ cw,
                                                __hip_bfloat16* __restrict__ bh,
                                                __hip_bfloat16* __restrict__ bl) {
    int o = blockIdx.x * 256 + threadIdx.x;   // 524288 total
    int e    = o & 7;
    int lane = (o >> 3) & 63;
    int s    = (o >> 9) & 63;
    int nt   = o >> 15;
    int n  = nt * 16 + (lane & 15);
    int j  = lane >> 4;
    int kk = s >> 2;
    int ic = (s & 3) * 32 + j * 8 + e;
    float v = cw[(n * NOC1 + ic) * 16 + kk];
    HL r = split2(v);
    ((short*)bh)[o] = r.hi;
    ((short*)bl)[o] = r.lo;
}

// ---------------- K2: WavConv via bf16 MFMA (3-term split) -----------------
__global__ __launch_bounds__(256, 2) void k_wavconv_mfma(
        const float* __restrict__ x,
        const __hip_bfloat16* __restrict__ bwh,
        const __hip_bfloat16* __restrict__ bwl,
        __hip_bfloat16* __restrict__ h2hi,
        __hip_bfloat16* __restrict__ h2lo) {
    __shared__ short xl[2][8][1512];   // 48384 B; slot(i) = i + 8*(i>>4)

    int tid = threadIdx.x;
    int b0  = blockIdx.x * 8;

    for (int i4 = tid; i4 < 2016; i4 += 256) {
        int b  = i4 / 252;
        int e4 = i4 - b * 252;
        float4 v = *(const float4*)(x + (size_t)(b0 + b) * XLEN + e4 * 4);
        int i    = e4 * 4;
        int slot = i + 8 * (i >> 4);
        HL r0 = split2(v.x);
        HL r1 = split2(v.y);
        HL r2 = split2(v.z);
        HL r3 = split2(v.w);
        short4v hv, lv;
        hv.x = r0.hi; hv.y = r1.hi; hv.z = r2.hi; hv.w = r3.hi;
        lv.x = r0.lo; lv.y = r1.lo; lv.z = r2.lo; lv.w = r3.lo;
        *(short4v*)&xl[0][b][slot] = hv;
        *(short4v*)&xl[1][b][slot] = lv;
    }
    __syncthreads();

    int lane = tid & 63;
    int w    = tid >> 6;     // 0..3
    int col  = lane & 15;
    int rg   = lane >> 4;    // 0..3

    f32x4 acc[4][8];
    f32x4 z = {0.f, 0.f, 0.f, 0.f};
#pragma unroll
    for (int tl = 0; tl < 4; ++tl)
#pragma unroll
        for (int nt = 0; nt < 8; ++nt) acc[tl][nt] = z;

    for (int s = 0; s < 16; ++s) {
        short8 Bh[8], Bl[8];
#pragma unroll
        for (int nt = 0; nt < 8; ++nt) {
            size_t off = ((size_t)(nt * 16 + s) * 64 + lane) * 8;
            Bh[nt] = *(const short8*)(bwh + off);
            Bl[nt] = *(const short8*)(bwl + off);
        }
#pragma unroll
        for (int tl = 0; tl < 4; ++tl) {
            int mt  = 4 * w + tl;
            int bl  = mt >> 1;
            int pos = (mt & 1) * 16 + col;
            int i    = (pos + 2 * s) * 16 + rg * 8;
            int slot = i + 8 * (i >> 4);
            short8 ah = *(const short8*)&xl[0][bl][slot];
            short8 al = *(const short8*)&xl[1][bl][slot];
#pragma unroll
            for (int nt = 0; nt < 8; ++nt) {
                acc[tl][nt] = __builtin_amdgcn_mfma_f32_16x16x32_bf16(ah, Bh[nt], acc[tl][nt], 0, 0, 0);
                acc[tl][nt] = __builtin_amdgcn_mfma_f32_16x16x32_bf16(ah, Bl[nt], acc[tl][nt], 0, 0, 0);
                acc[tl][nt] = __builtin_amdgcn_mfma_f32_16x16x32_bf16(al, Bh[nt], acc[tl][nt], 0, 0, 0);
            }
        }
    }

#pragma unroll
    for (int tl = 0; tl < 4; ++tl) {
        int mt = 4 * w + tl;
        int b  = b0 + (mt >> 1);
        int ph = (mt & 1) * 16;
#pragma unroll
        for (int nt = 0; nt < 8; ++nt) {
            int oc = nt * 16 + col;
#pragma unroll
            for (int r = 0; r < 4; ++r) {
                int pos = ph + rg * 4 + r;
                size_t off = ((size_t)b * NPOS + pos) * NOC1 + oc;
                HL rr = split2(acc[tl][nt][r]);
                ((short*)h2hi)[off] = rr.hi;
                ((short*)h2lo)[off] = rr.lo;
            }
        }
    }
}

// ---------------- K3: PrimaryCaps conv via bf16 MFMA (3-term split) + squash
__global__ __launch_bounds__(512) void k_conv_mfma(const __hip_bfloat16* __restrict__ h2hi,
                                                   const __hip_bfloat16* __restrict__ h2lo,
                                                   const __hip_bfloat16* __restrict__ bph,
                                                   const __hip_bfloat16* __restrict__ bpl,
                                                   const float* __restrict__ cb,
                                                   float* __restrict__ u) {
    __shared__ float smem[18432];            // 73728 B: A-staging, then p-exchange
    short* Alds  = (short*)smem;             // [2 variants][144 m][stride 40]
    float* p_lds = smem;                     // [16 b][1152]

    int tid  = threadIdx.x;
    int w    = tid >> 6;
    int lane = tid & 63;
    int col  = lane & 15;
    int rg   = lane >> 4;
    int b0   = blockIdx.x * 16;

    f32x4 acc0[9], acc1[9];
    f32x4 z = {0.f, 0.f, 0.f, 0.f};
#pragma unroll
    for (int mt = 0; mt < 9; ++mt) { acc0[mt] = z; acc1[mt] = z; }

    for (int s = 0; s < 64; ++s) {
        int kk  = s >> 2;
        int icb = (s & 3) * 32;
        __syncthreads();
        for (int idx = tid; idx < 1152; idx += 512) {
            int v  = idx >= 576;
            int j2 = idx - v * 576;
            int m  = j2 >> 2;
            int g  = j2 & 3;
            const __hip_bfloat16* src = (v ? h2lo : h2hi) +
                ((size_t)(b0 + (m & 15)) * NPOS + (2 * (m >> 4) + kk)) * NOC1 + icb + g * 8;
            short8 val = *(const short8*)src;
            *(short8*)&Alds[v * 5760 + m * 40 + g * 8] = val;
        }
        __syncthreads();

        size_t bo0 = ((size_t)(w * 64 + s) * 64 + lane) * 8;
        size_t bo1 = ((size_t)((8 + w) * 64 + s) * 64 + lane) * 8;
        short8 b0h = *(const short8*)(bph + bo0);
        short8 b0l = *(const short8*)(bpl + bo0);
        short8 b1h = *(const short8*)(bph + bo1);
        short8 b1l = *(const short8*)(bpl + bo1);

#pragma unroll
        for (int mt = 0; mt < 9; ++mt) {
            int aoff = (mt * 16 + col) * 40 + rg * 8;
            short8 ah = *(const short8*)&Alds[aoff];
            short8 al = *(const short8*)&Alds[5760 + aoff];
            acc0[mt] = __builtin_amdgcn_mfma_f32_16x16x32_bf16(ah, b0h, acc0[mt], 0, 0, 0);
            acc0[mt] = __builtin_amdgcn_mfma_f32_16x16x32_bf16(ah, b0l, acc0[mt], 0, 0, 0);
            acc0[mt] = __builtin_amdgcn_mfma_f32_16x16x32_bf16(al, b0h, acc0[mt], 0, 0, 0);
            acc1[mt] = __builtin_amdgcn_mfma_f32_16x16x32_bf16(ah, b1h, acc1[mt], 0, 0, 0);
            acc1[mt] = __builtin_amdgcn_mfma_f32_16x16x32_bf16(ah, b1l, acc1[mt], 0, 0, 0);
            acc1[mt] = __builtin_amdgcn_mfma_f32_16x16x32_bf16(al, b1h, acc1[mt], 0, 0, 0);
        }
    }
    __syncthreads();

    for (int ch = 0; ch < 2; ++ch) {
        int oc2l = w * 16 + col;
        float bias = cb[ch * 128 + oc2l];
        f32x4* accp = ch ? acc1 : acc0;
#pragma unroll
        for (int mt = 0; mt < 9; ++mt)
#pragma unroll
            for (int r = 0; r < 4; ++r) {
                int b = rg * 4 + r;
                p_lds[b * 1152 + oc2l * 9 + mt] = accp[mt][r] + bias;
            }
        __syncthreads();
        for (int idx = tid; idx < 2304; idx += 512) {
            int b  = idx / 144;
            int cl = idx - b * 144;
            float* pp = &p_lds[b * 1152 + cl * 8];
            float sn = 0.f;
#pragma unroll
            for (int i = 0; i < NDIM; ++i) sn = fmaf(pp[i], pp[i], sn);
            float sc = sn / (1.f + sn) / sqrtf(sn + 1e-8f);
            float* ug = u + ((size_t)(b0 + b) * (NCAPS * NDIM) + (ch * 144 + cl) * 8);
            float4 u0 = make_float4(pp[0] * sc, pp[1] * sc, pp[2] * sc, pp[3] * sc);
            float4 u1 = make_float4(pp[4] * sc, pp[5] * sc, pp[6] * sc, pp[7] * sc);
            ((float4*)ug)[0] = u0;
            ((float4*)ug)[1] = u1;
        }
        __syncthreads();
    }
}

// ---------------- K4: u_hat + routing, 2 batches/block, 512 threads --------
// Wave g owns caps [36g,36g+36): b_lds/c_lds for those caps are wave-private
// (written and read only by wave g) -> no block barrier around softmax or the
// agreement update. Only s_j reduce + v broadcast need __syncthreads (2/iter).
// Iter 0: softmax(0) == 0.25 exactly -> skip softmax and b_lds init.
__global__ __launch_bounds__(512, 4) void k_routing(const float* __restrict__ u,
                                                    const float* __restrict__ Wc,
                                                    float* __restrict__ out) {
    __shared__ float b_lds[2][NCAPS * 4];     // 9216 B
    __shared__ float c_lds[2][NCAPS * 4];     // 9216 B
    __shared__ float part_lds[2][512];        // 4096 B
    __shared__ float v_lds[2][64];            // 512 B

    int tid = threadIdx.x;
    int b0  = blockIdx.x * 2;

    int g = tid >> 6;
    int l = tid & 63;
    int d = l >> 4;
    int o = l & 15;
    int gu = __builtin_amdgcn_readfirstlane(g);   // wave-uniform -> s_load for u

    const float* ub0 = u + (size_t)(b0 + 0) * (NCAPS * NDIM) + gu * 36 * NDIM;
    const float* ub1 = u + (size_t)(b0 + 1) * (NCAPS * NDIM) + gu * 36 * NDIM;

    float uh0[36], uh1[36];
#pragma unroll
    for (int c = 0; c < 36; ++c) {
        int cap = gu * 36 + c;
        const float4* W4 = (const float4*)(Wc + ((size_t)cap * 512) + l * 8);
        float4 A  = W4[0];
        float4 Bv = W4[1];
        float t0 = A.x * ub0[c * 8 + 0];
        t0 = fmaf(A.y,  ub0[c * 8 + 1], t0);
        t0 = fmaf(A.z,  ub0[c * 8 + 2], t0);
        t0 = fmaf(A.w,  ub0[c * 8 + 3], t0);
        t0 = fmaf(Bv.x, ub0[c * 8 + 4], t0);
        t0 = fmaf(Bv.y, ub0[c * 8 + 5], t0);
        t0 = fmaf(Bv.z, ub0[c * 8 + 6], t0);
        t0 = fmaf(Bv.w, ub0[c * 8 + 7], t0);
        uh0[c] = t0;
        float t1 = A.x * ub1[c * 8 + 0];
        t1 = fmaf(A.y,  ub1[c * 8 + 1], t1);
        t1 = fmaf(A.z,  ub1[c * 8 + 2], t1);
        t1 = fmaf(A.w,  ub1[c * 8 + 3], t1);
        t1 = fmaf(Bv.x, ub1[c * 8 + 4], t1);
        t1 = fmaf(Bv.y, ub1[c * 8 + 5], t1);
        t1 = fmaf(Bv.z, ub1[c * 8 + 6], t1);
        t1 = fmaf(Bv.w, ub1[c * 8 + 7], t1);
        uh1[c] = t1;
    }

    for (int r = 0; r < 3; ++r) {
        if (r > 0) {
            __builtin_amdgcn_wave_barrier();
            // own-wave softmax over 72 (cap,batch) tasks
            for (int i = l; i < 72; i += 64) {
                int bb = (i >= 36) ? 1 : 0;
                int cl = i - bb * 36;
                int c  = gu * 36 + cl;
                float x0 = b_lds[bb][c * 4 + 0];
                float x1 = b_lds[bb][c * 4 + 1];
                float x2 = b_lds[bb][c * 4 + 2];
                float x3 = b_lds[bb][c * 4 + 3];
                float m  = fmaxf(fmaxf(x0, x1), fmaxf(x2, x3));
                float e0 = expf(x0 - m), e1 = expf(x1 - m);
                float e2 = expf(x2 - m), e3 = expf(x3 - m);
                float inv = 1.f / (e0 + e1 + e2 + e3);
                e0 *= inv; e1 *= inv; e2 *= inv; e3 *= inv;
                c_lds[bb][c * 4 + 0] = e0;
                c_lds[bb][c * 4 + 1] = e1;
                c_lds[bb][c * 4 + 2] = e2;
                c_lds[bb][c * 4 + 3] = e3;
                if (r == 2) {
                    *(float4*)(out + 16384 + ((size_t)(b0 + bb) * NCAPS + c) * 4) =
                        make_float4(e0, e1, e2, e3);
                }
            }
            __builtin_amdgcn_wave_barrier();
        }

        // s_j partials over this wave's 36 capsules, both batches
        float p0 = 0.f, p1 = 0.f;
        if (r == 0) {
#pragma unroll
            for (int c = 0; c < 36; ++c) {
                p0 = fmaf(0.25f, uh0[c], p0);
                p1 = fmaf(0.25f, uh1[c], p1);
            }
        } else {
#pragma unroll
            for (int c = 0; c < 36; ++c) {
                p0 = fmaf(c_lds[0][(g * 36 + c) * 4 + d], uh0[c], p0);
                p1 = fmaf(c_lds[1][(g * 36 + c) * 4 + d], uh1[c], p1);
            }
        }
        part_lds[0][tid] = p0;
        part_lds[1][tid] = p1;
        __syncthreads();

        if (tid < 128) {
            int bb = tid >> 6;
            int ll = tid & 63;
            float sv = 0.f;
#pragma unroll
            for (int k = 0; k < 8; ++k) sv += part_lds[bb][ll + 64 * k];
            float sq = sv * sv;
            sq += __shfl_xor(sq, 1);
            sq += __shfl_xor(sq, 2);
            sq += __shfl_xor(sq, 4);
            sq += __shfl_xor(sq, 8);
            float sc = sq / (1.f + sq) / sqrtf(sq + 1e-8f);
            float v  = sv * sc;
            v_lds[bb][ll] = v;
            if (r == 2) {
                float vv = v * v;
                vv += __shfl_xor(vv, 1);
                vv += __shfl_xor(vv, 2);
                vv += __shfl_xor(vv, 4);
                vv += __shfl_xor(vv, 8);
                if ((ll & 15) == 0)
                    out[(size_t)(b0 + bb) * 4 + (ll >> 4)] = sqrtf(vv);
            }
        }
        __syncthreads();

        if (r < 2) {
            float v0 = v_lds[0][l];
            float v1 = v_lds[1][l];
#pragma unroll
            for (int c = 0; c < 36; ++c) {
                float t0 = uh0[c] * v0;
                t0 += __shfl_xor(t0, 1);
                t0 += __shfl_xor(t0, 2);
                t0 += __shfl_xor(t0, 4);
                t0 += __shfl_xor(t0, 8);
                float t1 = uh1[c] * v1;
                t1 += __shfl_xor(t1, 1);
                t1 += __shfl_xor(t1, 2);
                t1 += __shfl_xor(t1, 4);
                t1 += __shfl_xor(t1, 8);
                if (o == 0) {
                    if (r == 0) {
                        b_lds[0][(g * 36 + c) * 4 + d] = t0;
                        b_lds[1][(g * 36 + c) * 4 + d] = t1;
                    } else {
                        b_lds[0][(g * 36 + c) * 4 + d] += t0;
                        b_lds[1][(g * 36 + c) * 4 + d] += t1;
                    }
                }
            }
        }
    }
}

extern "C" void kernel_launch(void* const* d_in, const int* in_sizes, int n_in,
                              void* d_out, int out_size, void* d_ws, size_t ws_size,
                              hipStream_t stream) {
    const float* x      = (const float*)d_in[0];
    const float* a      = (const float*)d_in[1];
    const float* w      = (const float*)d_in[2];
    const float* conv_w = (const float*)d_in[3];
    const float* conv_b = (const float*)d_in[4];
    const float* W_caps = (const float*)d_in[5];
    float* out = (float*)d_out;
    char* ws   = (char*)d_ws;

    __hip_bfloat16*  bwh  = (__hip_bfloat16*)(ws + BWH_OFF);
    __hip_bfloat16*  bwl  = (__hip_bfloat16*)(ws + BWL_OFF);
    __hip_bfloat16*  bph  = (__hip_bfloat16*)(ws + BPH_OFF);
    __hip_bfloat16*  bpl  = (__hip_bfloat16*)(ws + BPL_OFF);
    __hip_bfloat16*  h2hi = (__hip_bfloat16*)(ws + H2HI_OFF);
    __hip_bfloat16*  h2lo = (__hip_bfloat16*)(ws + H2LO_OFF);
    float*           u    = (float*)(ws + U_OFF);

    k_wav_pack<<<256, 256, 0, stream>>>(a, w, bwh, bwl);
    k_pack_b<<<2048, 256, 0, stream>>>(conv_w, bph, bpl);
    k_wavconv_mfma<<<BATCH / 8, 256, 0, stream>>>(x, bwh, bwl, h2hi, h2lo);
    k_conv_mfma<<<BATCH / 16, 512, 0, stream>>>(h2hi, h2lo, bph, bpl, conv_b, u);
    k_routing<<<BATCH / 2, 512, 0, stream>>>(u, W_caps, out);
}

// Round 8
// 358.396 us; speedup vs baseline: 11.8516x; 1.1727x over previous
//
#include <hip/hip_runtime.h>
#include <hip/hip_bf16.h>
#include <math.h>

typedef __attribute__((ext_vector_type(4))) short short4v;
typedef __attribute__((ext_vector_type(8))) short short8;
typedef __attribute__((ext_vector_type(4))) float f32x4;

#define BATCH   4096
#define XLEN    1008
#define NOC1    128
#define NPOS    32
#define NOC2    256
#define NQ      9
#define NCAPS   288
#define NDIM    8

// ws layout (bytes)
#define BWH_OFF   0           // wavelet B-pack hi bf16, 128 KB
#define BWL_OFF   131072      // wavelet B-pack lo bf16, 128 KB
#define BPH_OFF   262144      // conv2 B-pack hi bf16, 1 MB
#define BPL_OFF   1310720     // conv2 B-pack lo bf16, 1 MB
#define H2HI_OFF  2359296     // h2 hi bf16 [b][pos32][ic128], 33.55 MB
#define H2LO_OFF  35913728    // h2 lo bf16, 33.55 MB
#define U_OFF     69468160    // u fp32 [b][288][8], 37.75 MB

struct HL { short hi, lo; };

static __device__ inline HL split2(float v) {
    HL r;
    __hip_bfloat16 h = __float2bfloat16(v);
    r.hi = *reinterpret_cast<short*>(&h);
    float rem = v - __bfloat162float(h);
    __hip_bfloat16 l = __float2bfloat16(rem);
    r.lo = *reinterpret_cast<short*>(&l);
    return r;
}

// DPP 16-lane (row) sum — VALU pipe, no LDS. Bitwise == shfl_xor 1/2/4/8 tree.
template <int CTRL>
static __device__ __forceinline__ float dpp_addf(float x) {
    int y = __builtin_amdgcn_update_dpp(0, __builtin_bit_cast(int, x),
                                        CTRL, 0xf, 0xf, true);
    return x + __builtin_bit_cast(float, y);
}
static __device__ __forceinline__ float rowsum16(float x) {
    x = dpp_addf<0xB1>(x);    // quad_perm [1,0,3,2]  (xor 1)
    x = dpp_addf<0x4E>(x);    // quad_perm [2,3,0,1]  (xor 2)
    x = dpp_addf<0x141>(x);   // row_half_mirror      (~xor 4 after quad sums)
    x = dpp_addf<0x140>(x);   // row_mirror           (~xor 8 after half sums)
    return x;
}

// ---------------- K1a: wavelet weights directly in MFMA B-fragment order ---
__global__ __launch_bounds__(256) void k_wav_pack(const float* __restrict__ a,
                                                  const float* __restrict__ w,
                                                  __hip_bfloat16* __restrict__ bh,
                                                  __hip_bfloat16* __restrict__ bl) {
    int idx = blockIdx.x * 256 + threadIdx.x;   // 65536 total
    int e    = idx & 7;
    int lane = (idx >> 3) & 63;
    int s    = (idx >> 9) & 15;
    int nt   = idx >> 13;
    int oc = nt * 16 + (lane & 15);
    int k  = s * 32 + (lane >> 4) * 8 + e;
    float t  = -1.0f + 2.0f * (float)k / 511.0f;
    float av = fmaxf(a[oc], 1e-5f);
    float ts = t / av;
    float v = cosf(w[oc] * t) * expf(-0.5f * ts * ts);
    HL r = split2(v);
    ((short*)bh)[idx] = r.hi;
    ((short*)bl)[idx] = r.lo;
}

// ---------------- K1b: pack conv_w into MFMA B-fragment order, bf16 hi/lo --
__global__ __launch_bounds__(256) void k_pack_b(const float* __restrict__ cw,
                                                __hip_bfloat16* __restrict__ bh,
                                                __hip_bfloat16* __restrict__ bl) {
    int o = blockIdx.x * 256 + threadIdx.x;   // 524288 total
    int e    = o & 7;
    int lane = (o >> 3) & 63;
    int s    = (o >> 9) & 63;
    int nt   = o >> 15;
    int n  = nt * 16 + (lane & 15);
    int j  = lane >> 4;
    int kk = s >> 2;
    int ic = (s & 3) * 32 + j * 8 + e;
    float v = cw[(n * NOC1 + ic) * 16 + kk];
    HL r = split2(v);
    ((short*)bh)[o] = r.hi;
    ((short*)bl)[o] = r.lo;
}

// ---------------- K2: WavConv via bf16 MFMA (3-term split) -----------------
__global__ __launch_bounds__(256, 2) void k_wavconv_mfma(
        const float* __restrict__ x,
        const __hip_bfloat16* __restrict__ bwh,
        const __hip_bfloat16* __restrict__ bwl,
        __hip_bfloat16* __restrict__ h2hi,
        __hip_bfloat16* __restrict__ h2lo) {
    __shared__ short xl[2][8][1512];   // 48384 B; slot(i) = i + 8*(i>>4)

    int tid = threadIdx.x;
    int b0  = blockIdx.x * 8;

    for (int i4 = tid; i4 < 2016; i4 += 256) {
        int b  = i4 / 252;
        int e4 = i4 - b * 252;
        float4 v = *(const float4*)(x + (size_t)(b0 + b) * XLEN + e4 * 4);
        int i    = e4 * 4;
        int slot = i + 8 * (i >> 4);
        HL r0 = split2(v.x);
        HL r1 = split2(v.y);
        HL r2 = split2(v.z);
        HL r3 = split2(v.w);
        short4v hv, lv;
        hv.x = r0.hi; hv.y = r1.hi; hv.z = r2.hi; hv.w = r3.hi;
        lv.x = r0.lo; lv.y = r1.lo; lv.z = r2.lo; lv.w = r3.lo;
        *(short4v*)&xl[0][b][slot] = hv;
        *(short4v*)&xl[1][b][slot] = lv;
    }
    __syncthreads();

    int lane = tid & 63;
    int w    = tid >> 6;     // 0..3
    int col  = lane & 15;
    int rg   = lane >> 4;    // 0..3

    f32x4 acc[4][8];
    f32x4 z = {0.f, 0.f, 0.f, 0.f};
#pragma unroll
    for (int tl = 0; tl < 4; ++tl)
#pragma unroll
        for (int nt = 0; nt < 8; ++nt) acc[tl][nt] = z;

    for (int s = 0; s < 16; ++s) {
        short8 Bh[8], Bl[8];
#pragma unroll
        for (int nt = 0; nt < 8; ++nt) {
            size_t off = ((size_t)(nt * 16 + s) * 64 + lane) * 8;
            Bh[nt] = *(const short8*)(bwh + off);
            Bl[nt] = *(const short8*)(bwl + off);
        }
#pragma unroll
        for (int tl = 0; tl < 4; ++tl) {
            int mt  = 4 * w + tl;
            int bl  = mt >> 1;
            int pos = (mt & 1) * 16 + col;
            int i    = (pos + 2 * s) * 16 + rg * 8;
            int slot = i + 8 * (i >> 4);
            short8 ah = *(const short8*)&xl[0][bl][slot];
            short8 al = *(const short8*)&xl[1][bl][slot];
#pragma unroll
            for (int nt = 0; nt < 8; ++nt) {
                acc[tl][nt] = __builtin_amdgcn_mfma_f32_16x16x32_bf16(ah, Bh[nt], acc[tl][nt], 0, 0, 0);
                acc[tl][nt] = __builtin_amdgcn_mfma_f32_16x16x32_bf16(ah, Bl[nt], acc[tl][nt], 0, 0, 0);
                acc[tl][nt] = __builtin_amdgcn_mfma_f32_16x16x32_bf16(al, Bh[nt], acc[tl][nt], 0, 0, 0);
            }
        }
    }

#pragma unroll
    for (int tl = 0; tl < 4; ++tl) {
        int mt = 4 * w + tl;
        int b  = b0 + (mt >> 1);
        int ph = (mt & 1) * 16;
#pragma unroll
        for (int nt = 0; nt < 8; ++nt) {
            int oc = nt * 16 + col;
#pragma unroll
            for (int r = 0; r < 4; ++r) {
                int pos = ph + rg * 4 + r;
                size_t off = ((size_t)b * NPOS + pos) * NOC1 + oc;
                HL rr = split2(acc[tl][nt][r]);
                ((short*)h2hi)[off] = rr.hi;
                ((short*)h2lo)[off] = rr.lo;
            }
        }
    }
}

// ---------------- K3: PrimaryCaps conv via bf16 MFMA (3-term split) + squash
__global__ __launch_bounds__(512) void k_conv_mfma(const __hip_bfloat16* __restrict__ h2hi,
                                                   const __hip_bfloat16* __restrict__ h2lo,
                                                   const __hip_bfloat16* __restrict__ bph,
                                                   const __hip_bfloat16* __restrict__ bpl,
                                                   const float* __restrict__ cb,
                                                   float* __restrict__ u) {
    __shared__ float smem[18432];            // 73728 B: A-staging, then p-exchange
    short* Alds  = (short*)smem;             // [2 variants][144 m][stride 40]
    float* p_lds = smem;                     // [16 b][1152]

    int tid  = threadIdx.x;
    int w    = tid >> 6;
    int lane = tid & 63;
    int col  = lane & 15;
    int rg   = lane >> 4;
    int b0   = blockIdx.x * 16;

    f32x4 acc0[9], acc1[9];
    f32x4 z = {0.f, 0.f, 0.f, 0.f};
#pragma unroll
    for (int mt = 0; mt < 9; ++mt) { acc0[mt] = z; acc1[mt] = z; }

    for (int s = 0; s < 64; ++s) {
        int kk  = s >> 2;
        int icb = (s & 3) * 32;
        __syncthreads();
        for (int idx = tid; idx < 1152; idx += 512) {
            int v  = idx >= 576;
            int j2 = idx - v * 576;
            int m  = j2 >> 2;
            int g  = j2 & 3;
            const __hip_bfloat16* src = (v ? h2lo : h2hi) +
                ((size_t)(b0 + (m & 15)) * NPOS + (2 * (m >> 4) + kk)) * NOC1 + icb + g * 8;
            short8 val = *(const short8*)src;
            *(short8*)&Alds[v * 5760 + m * 40 + g * 8] = val;
        }
        __syncthreads();

        size_t bo0 = ((size_t)(w * 64 + s) * 64 + lane) * 8;
        size_t bo1 = ((size_t)((8 + w) * 64 + s) * 64 + lane) * 8;
        short8 b0h = *(const short8*)(bph + bo0);
        short8 b0l = *(const short8*)(bpl + bo0);
        short8 b1h = *(const short8*)(bph + bo1);
        short8 b1l = *(const short8*)(bpl + bo1);

#pragma unroll
        for (int mt = 0; mt < 9; ++mt) {
            int aoff = (mt * 16 + col) * 40 + rg * 8;
            short8 ah = *(const short8*)&Alds[aoff];
            short8 al = *(const short8*)&Alds[5760 + aoff];
            acc0[mt] = __builtin_amdgcn_mfma_f32_16x16x32_bf16(ah, b0h, acc0[mt], 0, 0, 0);
            acc0[mt] = __builtin_amdgcn_mfma_f32_16x16x32_bf16(ah, b0l, acc0[mt], 0, 0, 0);
            acc0[mt] = __builtin_amdgcn_mfma_f32_16x16x32_bf16(al, b0h, acc0[mt], 0, 0, 0);
            acc1[mt] = __builtin_amdgcn_mfma_f32_16x16x32_bf16(ah, b1h, acc1[mt], 0, 0, 0);
            acc1[mt] = __builtin_amdgcn_mfma_f32_16x16x32_bf16(ah, b1l, acc1[mt], 0, 0, 0);
            acc1[mt] = __builtin_amdgcn_mfma_f32_16x16x32_bf16(al, b1h, acc1[mt], 0, 0, 0);
        }
    }
    __syncthreads();

    for (int ch = 0; ch < 2; ++ch) {
        int oc2l = w * 16 + col;
        float bias = cb[ch * 128 + oc2l];
        f32x4* accp = ch ? acc1 : acc0;
#pragma unroll
        for (int mt = 0; mt < 9; ++mt)
#pragma unroll
            for (int r = 0; r < 4; ++r) {
                int b = rg * 4 + r;
                p_lds[b * 1152 + oc2l * 9 + mt] = accp[mt][r] + bias;
            }
        __syncthreads();
        for (int idx = tid; idx < 2304; idx += 512) {
            int b  = idx / 144;
            int cl = idx - b * 144;
            float* pp = &p_lds[b * 1152 + cl * 8];
            float sn = 0.f;
#pragma unroll
            for (int i = 0; i < NDIM; ++i) sn = fmaf(pp[i], pp[i], sn);
            float sc = sn / (1.f + sn) / sqrtf(sn + 1e-8f);
            float* ug = u + ((size_t)(b0 + b) * (NCAPS * NDIM) + (ch * 144 + cl) * 8);
            float4 u0 = make_float4(pp[0] * sc, pp[1] * sc, pp[2] * sc, pp[3] * sc);
            float4 u1 = make_float4(pp[4] * sc, pp[5] * sc, pp[6] * sc, pp[7] * sc);
            ((float4*)ug)[0] = u0;
            ((float4*)ug)[1] = u1;
        }
        __syncthreads();
    }
}

// ---------------- K4: u_hat + routing, 2 batches/block, 512 threads --------
// All 16-lane reductions via DPP (VALU pipe). Softmax I/O as float4.
__global__ __launch_bounds__(512, 4) void k_routing(const float* __restrict__ u,
                                                    const float* __restrict__ Wc,
                                                    float* __restrict__ out) {
    __shared__ float b_lds[2][NCAPS * 4];     // 9216 B
    __shared__ float c_lds[2][NCAPS * 4];     // 9216 B
    __shared__ float part_lds[2][512];        // 4096 B
    __shared__ float v_lds[2][64];            // 512 B

    int tid = threadIdx.x;
    int b0  = blockIdx.x * 2;

    int g = tid >> 6;
    int l = tid & 63;
    int d = l >> 4;
    int o = l & 15;
    int gu = __builtin_amdgcn_readfirstlane(g);   // wave-uniform -> s_load for u

    const float* ub0 = u + (size_t)(b0 + 0) * (NCAPS * NDIM) + gu * 36 * NDIM;
    const float* ub1 = u + (size_t)(b0 + 1) * (NCAPS * NDIM) + gu * 36 * NDIM;

    float uh0[36], uh1[36];
#pragma unroll
    for (int c = 0; c < 36; ++c) {
        int cap = gu * 36 + c;
        const float4* W4 = (const float4*)(Wc + ((size_t)cap * 512) + l * 8);
        float4 A  = W4[0];
        float4 Bv = W4[1];
        float t0 = A.x * ub0[c * 8 + 0];
        t0 = fmaf(A.y,  ub0[c * 8 + 1], t0);
        t0 = fmaf(A.z,  ub0[c * 8 + 2], t0);
        t0 = fmaf(A.w,  ub0[c * 8 + 3], t0);
        t0 = fmaf(Bv.x, ub0[c * 8 + 4], t0);
        t0 = fmaf(Bv.y, ub0[c * 8 + 5], t0);
        t0 = fmaf(Bv.z, ub0[c * 8 + 6], t0);
        t0 = fmaf(Bv.w, ub0[c * 8 + 7], t0);
        uh0[c] = t0;
        float t1 = A.x * ub1[c * 8 + 0];
        t1 = fmaf(A.y,  ub1[c * 8 + 1], t1);
        t1 = fmaf(A.z,  ub1[c * 8 + 2], t1);
        t1 = fmaf(A.w,  ub1[c * 8 + 3], t1);
        t1 = fmaf(Bv.x, ub1[c * 8 + 4], t1);
        t1 = fmaf(Bv.y, ub1[c * 8 + 5], t1);
        t1 = fmaf(Bv.z, ub1[c * 8 + 6], t1);
        t1 = fmaf(Bv.w, ub1[c * 8 + 7], t1);
        uh1[c] = t1;
    }

    for (int r = 0; r < 3; ++r) {
        if (r > 0) {
            __builtin_amdgcn_wave_barrier();
            // own-wave softmax over 72 (cap,batch) tasks, float4 LDS I/O
            for (int i = l; i < 72; i += 64) {
                int bb = (i >= 36) ? 1 : 0;
                int cl = i - bb * 36;
                int c  = gu * 36 + cl;
                float4 bv = *(const float4*)&b_lds[bb][c * 4];
                float m  = fmaxf(fmaxf(bv.x, bv.y), fmaxf(bv.z, bv.w));
                float e0 = expf(bv.x - m), e1 = expf(bv.y - m);
                float e2 = expf(bv.z - m), e3 = expf(bv.w - m);
                float inv = 1.f / (e0 + e1 + e2 + e3);
                e0 *= inv; e1 *= inv; e2 *= inv; e3 *= inv;
                *(float4*)&c_lds[bb][c * 4] = make_float4(e0, e1, e2, e3);
                if (r == 2) {
                    *(float4*)(out + 16384 + ((size_t)(b0 + bb) * NCAPS + c) * 4) =
                        make_float4(e0, e1, e2, e3);
                }
            }
            __builtin_amdgcn_wave_barrier();
        }

        // s_j partials over this wave's 36 capsules, both batches
        float p0 = 0.f, p1 = 0.f;
        if (r == 0) {
#pragma unroll
            for (int c = 0; c < 36; ++c) {
                p0 = fmaf(0.25f, uh0[c], p0);
                p1 = fmaf(0.25f, uh1[c], p1);
            }
        } else {
#pragma unroll
            for (int c = 0; c < 36; ++c) {
                p0 = fmaf(c_lds[0][(g * 36 + c) * 4 + d], uh0[c], p0);
                p1 = fmaf(c_lds[1][(g * 36 + c) * 4 + d], uh1[c], p1);
            }
        }
        part_lds[0][tid] = p0;
        part_lds[1][tid] = p1;
        __syncthreads();

        if (tid < 128) {
            int bb = tid >> 6;
            int ll = tid & 63;
            float sv = 0.f;
#pragma unroll
            for (int k = 0; k < 8; ++k) sv += part_lds[bb][ll + 64 * k];
            float sq = rowsum16(sv * sv);
            float sc = sq / (1.f + sq) / sqrtf(sq + 1e-8f);
            float v  = sv * sc;
            v_lds[bb][ll] = v;
            if (r == 2) {
                float vv = rowsum16(v * v);
                if ((ll & 15) == 0)
                    out[(size_t)(b0 + bb) * 4 + (ll >> 4)] = sqrtf(vv);
            }
        }
        __syncthreads();

        if (r < 2) {
            float v0 = v_lds[0][l];
            float v1 = v_lds[1][l];
#pragma unroll
            for (int c = 0; c < 36; ++c) {
                float t0 = rowsum16(uh0[c] * v0);
                float t1 = rowsum16(uh1[c] * v1);
                if (o == 0) {
                    if (r == 0) {
                        b_lds[0][(g * 36 + c) * 4 + d] = t0;
                        b_lds[1][(g * 36 + c) * 4 + d] = t1;
                    } else {
                        b_lds[0][(g * 36 + c) * 4 + d] += t0;
                        b_lds[1][(g * 36 + c) * 4 + d] += t1;
                    }
                }
            }
        }
    }
}

extern "C" void kernel_launch(void* const* d_in, const int* in_sizes, int n_in,
                              void* d_out, int out_size, void* d_ws, size_t ws_size,
                              hipStream_t stream) {
    const float* x      = (const float*)d_in[0];
    const float* a      = (const float*)d_in[1];
    const float* w      = (const float*)d_in[2];
    const float* conv_w = (const float*)d_in[3];
    const float* conv_b = (const float*)d_in[4];
    const float* W_caps = (const float*)d_in[5];
    float* out = (float*)d_out;
    char* ws   = (char*)d_ws;

    __hip_bfloat16*  bwh  = (__hip_bfloat16*)(ws + BWH_OFF);
    __hip_bfloat16*  bwl  = (__hip_bfloat16*)(ws + BWL_OFF);
    __hip_bfloat16*  bph  = (__hip_bfloat16*)(ws + BPH_OFF);
    __hip_bfloat16*  bpl  = (__hip_bfloat16*)(ws + BPL_OFF);
    __hip_bfloat16*  h2hi = (__hip_bfloat16*)(ws + H2HI_OFF);
    __hip_bfloat16*  h2lo = (__hip_bfloat16*)(ws + H2LO_OFF);
    float*           u    = (float*)(ws + U_OFF);

    k_wav_pack<<<256, 256, 0, stream>>>(a, w, bwh, bwl);
    k_pack_b<<<2048, 256, 0, stream>>>(conv_w, bph, bpl);
    k_wavconv_mfma<<<BATCH / 8, 256, 0, stream>>>(x, bwh, bwl, h2hi, h2lo);
    k_conv_mfma<<<BATCH / 16, 512, 0, stream>>>(h2hi, h2lo, bph, bpl, conv_b, u);
    k_routing<<<BATCH / 2, 512, 0, stream>>>(u, W_caps, out);
}

// Round 9
// 336.544 us; speedup vs baseline: 12.6211x; 1.0649x over previous
//
#include <hip/hip_runtime.h>
#include <hip/hip_bf16.h>
#include <math.h>

typedef __attribute__((ext_vector_type(4))) short short4v;
typedef __attribute__((ext_vector_type(8))) short short8;
typedef __attribute__((ext_vector_type(4))) float f32x4;

#define BATCH   4096
#define XLEN    1008
#define NOC1    128
#define NPOS    32
#define NOC2    256
#define NQ      9
#define NCAPS   288
#define NDIM    8

// ws layout (bytes)
#define BWH_OFF   0           // wavelet B-pack hi bf16, 128 KB
#define BWL_OFF   131072      // wavelet B-pack lo bf16, 128 KB
#define BPH_OFF   262144      // conv2 B-pack hi bf16, 1 MB
#define BPL_OFF   1310720     // conv2 B-pack lo bf16, 1 MB
#define H2HI_OFF  2359296     // h2 hi bf16 [b][pos32][ic128], 33.55 MB
#define H2LO_OFF  35913728    // h2 lo bf16, 33.55 MB
#define U_OFF     69468160    // u fp32 [b][288][8], 37.75 MB

struct HL { short hi, lo; };

static __device__ inline HL split2(float v) {
    HL r;
    __hip_bfloat16 h = __float2bfloat16(v);
    r.hi = *reinterpret_cast<short*>(&h);
    float rem = v - __bfloat162float(h);
    __hip_bfloat16 l = __float2bfloat16(rem);
    r.lo = *reinterpret_cast<short*>(&l);
    return r;
}

// DPP 16-lane (row) sum — VALU pipe, no LDS. Bitwise == shfl_xor 1/2/4/8 tree.
template <int CTRL>
static __device__ __forceinline__ float dpp_addf(float x) {
    int y = __builtin_amdgcn_update_dpp(0, __builtin_bit_cast(int, x),
                                        CTRL, 0xf, 0xf, true);
    return x + __builtin_bit_cast(float, y);
}
static __device__ __forceinline__ float rowsum16(float x) {
    x = dpp_addf<0xB1>(x);    // quad_perm xor1
    x = dpp_addf<0x4E>(x);    // quad_perm xor2
    x = dpp_addf<0x141>(x);   // row_half_mirror
    x = dpp_addf<0x140>(x);   // row_mirror
    return x;
}

// ---------------- K1a: wavelet weights directly in MFMA B-fragment order ---
__global__ __launch_bounds__(256) void k_wav_pack(const float* __restrict__ a,
                                                  const float* __restrict__ w,
                                                  __hip_bfloat16* __restrict__ bh,
                                                  __hip_bfloat16* __restrict__ bl) {
    int idx = blockIdx.x * 256 + threadIdx.x;   // 65536 total
    int e    = idx & 7;
    int lane = (idx >> 3) & 63;
    int s    = (idx >> 9) & 15;
    int nt   = idx >> 13;
    int oc = nt * 16 + (lane & 15);
    int k  = s * 32 + (lane >> 4) * 8 + e;
    float t  = -1.0f + 2.0f * (float)k / 511.0f;
    float av = fmaxf(a[oc], 1e-5f);
    float ts = t / av;
    float v = cosf(w[oc] * t) * expf(-0.5f * ts * ts);
    HL r = split2(v);
    ((short*)bh)[idx] = r.hi;
    ((short*)bl)[idx] = r.lo;
}

// ---------------- K1b: pack conv_w into MFMA B-fragment order, bf16 hi/lo --
__global__ __launch_bounds__(256) void k_pack_b(const float* __restrict__ cw,
                                                __hip_bfloat16* __restrict__ bh,
                                                __hip_bfloat16* __restrict__ bl) {
    int o = blockIdx.x * 256 + threadIdx.x;   // 524288 total
    int e    = o & 7;
    int lane = (o >> 3) & 63;
    int s    = (o >> 9) & 63;
    int nt   = o >> 15;
    int n  = nt * 16 + (lane & 15);
    int j  = lane >> 4;
    int kk = s >> 2;
    int ic = (s & 3) * 32 + j * 8 + e;
    float v = cw[(n * NOC1 + ic) * 16 + kk];
    HL r = split2(v);
    ((short*)bh)[o] = r.hi;
    ((short*)bl)[o] = r.lo;
}

// ---------------- K2: WavConv via bf16 MFMA (3-term split) -----------------
__global__ __launch_bounds__(256, 2) void k_wavconv_mfma(
        const float* __restrict__ x,
        const __hip_bfloat16* __restrict__ bwh,
        const __hip_bfloat16* __restrict__ bwl,
        __hip_bfloat16* __restrict__ h2hi,
        __hip_bfloat16* __restrict__ h2lo) {
    __shared__ short xl[2][8][1512];   // 48384 B; slot(i) = i + 8*(i>>4)

    int tid = threadIdx.x;
    int b0  = blockIdx.x * 8;

    for (int i4 = tid; i4 < 2016; i4 += 256) {
        int b  = i4 / 252;
        int e4 = i4 - b * 252;
        float4 v = *(const float4*)(x + (size_t)(b0 + b) * XLEN + e4 * 4);
        int i    = e4 * 4;
        int slot = i + 8 * (i >> 4);
        HL r0 = split2(v.x);
        HL r1 = split2(v.y);
        HL r2 = split2(v.z);
        HL r3 = split2(v.w);
        short4v hv, lv;
        hv.x = r0.hi; hv.y = r1.hi; hv.z = r2.hi; hv.w = r3.hi;
        lv.x = r0.lo; lv.y = r1.lo; lv.z = r2.lo; lv.w = r3.lo;
        *(short4v*)&xl[0][b][slot] = hv;
        *(short4v*)&xl[1][b][slot] = lv;
    }
    __syncthreads();

    int lane = tid & 63;
    int w    = tid >> 6;     // 0..3
    int col  = lane & 15;
    int rg   = lane >> 4;    // 0..3

    f32x4 acc[4][8];
    f32x4 z = {0.f, 0.f, 0.f, 0.f};
#pragma unroll
    for (int tl = 0; tl < 4; ++tl)
#pragma unroll
        for (int nt = 0; nt < 8; ++nt) acc[tl][nt] = z;

    for (int s = 0; s < 16; ++s) {
        short8 Bh[8], Bl[8];
#pragma unroll
        for (int nt = 0; nt < 8; ++nt) {
            size_t off = ((size_t)(nt * 16 + s) * 64 + lane) * 8;
            Bh[nt] = *(const short8*)(bwh + off);
            Bl[nt] = *(const short8*)(bwl + off);
        }
#pragma unroll
        for (int tl = 0; tl < 4; ++tl) {
            int mt  = 4 * w + tl;
            int bl  = mt >> 1;
            int pos = (mt & 1) * 16 + col;
            int i    = (pos + 2 * s) * 16 + rg * 8;
            int slot = i + 8 * (i >> 4);
            short8 ah = *(const short8*)&xl[0][bl][slot];
            short8 al = *(const short8*)&xl[1][bl][slot];
#pragma unroll
            for (int nt = 0; nt < 8; ++nt) {
                acc[tl][nt] = __builtin_amdgcn_mfma_f32_16x16x32_bf16(ah, Bh[nt], acc[tl][nt], 0, 0, 0);
                acc[tl][nt] = __builtin_amdgcn_mfma_f32_16x16x32_bf16(ah, Bl[nt], acc[tl][nt], 0, 0, 0);
                acc[tl][nt] = __builtin_amdgcn_mfma_f32_16x16x32_bf16(al, Bh[nt], acc[tl][nt], 0, 0, 0);
            }
        }
    }

#pragma unroll
    for (int tl = 0; tl < 4; ++tl) {
        int mt = 4 * w + tl;
        int b  = b0 + (mt >> 1);
        int ph = (mt & 1) * 16;
#pragma unroll
        for (int nt = 0; nt < 8; ++nt) {
            int oc = nt * 16 + col;
#pragma unroll
            for (int r = 0; r < 4; ++r) {
                int pos = ph + rg * 4 + r;
                size_t off = ((size_t)b * NPOS + pos) * NOC1 + oc;
                HL rr = split2(acc[tl][nt][r]);
                ((short*)h2hi)[off] = rr.hi;
                ((short*)h2lo)[off] = rr.lo;
            }
        }
    }
}

// ---------------- K3: PrimaryCaps conv via bf16 MFMA + squash --------------
// 8 batches/block, grid 512 (2 blocks/CU). 512 threads, 8 waves.
// M = 72 rows (m = q*8 + b, q=0..8) padded to 5 m-tiles; wave w owns n-tiles
// {w, 8+w}. K in 32 double-steps (kk 0..15 x two 64-ic halves), BK=64.
// A-stage: rows of 64 shorts, stride 72 (144B == 4 banks): stage writes with
// consecutive lanes -> consecutive m, reads (mt*16+col)*72 -> both phases hit
// banks {0,4,...,28}: conflict-free.
__global__ __launch_bounds__(512, 4) void k_conv_mfma(const __hip_bfloat16* __restrict__ h2hi,
                                                      const __hip_bfloat16* __restrict__ h2lo,
                                                      const __hip_bfloat16* __restrict__ bph,
                                                      const __hip_bfloat16* __restrict__ bpl,
                                                      const float* __restrict__ cb,
                                                      float* __restrict__ u) {
    __shared__ char smem[36864];     // k-loop: A-stage (23040 B); epilogue: p_lds
    short* Alds  = (short*)smem;     // [2 v][80 rows][stride 72]
    float* p_lds = (float*)smem;     // [8 b][1152]

    int tid  = threadIdx.x;
    int w    = tid >> 6;
    int lane = tid & 63;
    int col  = lane & 15;
    int rg   = lane >> 4;
    int b0   = blockIdx.x * 8;

    f32x4 acc[5][2];
    f32x4 z = {0.f, 0.f, 0.f, 0.f};
#pragma unroll
    for (int mt = 0; mt < 5; ++mt) { acc[mt][0] = z; acc[mt][1] = z; }

    for (int t = 0; t < 32; ++t) {
        int kk = t >> 1;
        int hb = (t & 1) * 64;          // ic base of this 64-wide half
        __syncthreads();
        // stage 2v x 72 rows x 64 shorts (8 b128 chunks per row), transposed
        for (int idx = tid; idx < 1152; idx += 512) {
            int m  = idx % 72;
            int r2 = idx / 72;          // 0..15
            int g  = r2 & 7;
            int v  = r2 >> 3;
            const __hip_bfloat16* src = (v ? h2lo : h2hi) +
                ((size_t)(b0 + (m & 7)) * NPOS + (2 * (m >> 3) + kk)) * NOC1 + hb + g * 8;
            *(short8*)&Alds[v * 5760 + m * 72 + g * 8] = *(const short8*)src;
        }
        __syncthreads();

        // B fragments: sub-steps j=0,1 -> original s = kk*4 + (t&1)*2 + j
        int sbase = kk * 4 + (t & 1) * 2;
        short8 Bh[2][2], Bl[2][2];
#pragma unroll
        for (int n = 0; n < 2; ++n) {
            int nt = w + n * 8;
#pragma unroll
            for (int j = 0; j < 2; ++j) {
                size_t bo = ((size_t)(nt * 64 + sbase + j) * 64 + lane) * 8;
                Bh[n][j] = *(const short8*)(bph + bo);
                Bl[n][j] = *(const short8*)(bpl + bo);
            }
        }

#pragma unroll
        for (int j = 0; j < 2; ++j)
#pragma unroll
            for (int mt = 0; mt < 5; ++mt) {
                int aoff = (mt * 16 + col) * 72 + j * 32 + rg * 8;
                short8 ah = *(const short8*)&Alds[aoff];
                short8 al = *(const short8*)&Alds[5760 + aoff];
#pragma unroll
                for (int n = 0; n < 2; ++n) {
                    acc[mt][n] = __builtin_amdgcn_mfma_f32_16x16x32_bf16(ah, Bh[n][j], acc[mt][n], 0, 0, 0);
                    acc[mt][n] = __builtin_amdgcn_mfma_f32_16x16x32_bf16(ah, Bl[n][j], acc[mt][n], 0, 0, 0);
                    acc[mt][n] = __builtin_amdgcn_mfma_f32_16x16x32_bf16(al, Bh[n][j], acc[mt][n], 0, 0, 0);
                }
            }
    }
    __syncthreads();

    // Epilogue per 128-oc2 chunk. C/D: col = n within tile, row = rg*4 + r.
    for (int ch = 0; ch < 2; ++ch) {
        int oc2l = w * 16 + col;                // chunk-local oc2 (tile ch*8+w)
        float bias = cb[ch * 128 + oc2l];
#pragma unroll
        for (int mt = 0; mt < 5; ++mt)
#pragma unroll
            for (int r = 0; r < 4; ++r) {
                int m = mt * 16 + rg * 4 + r;
                if (m < 72) {
                    int q = m >> 3;
                    int b = m & 7;
                    p_lds[b * 1152 + oc2l * 9 + q] = acc[mt][ch][r] + bias;
                }
            }
        __syncthreads();
        for (int idx = tid; idx < 1152; idx += 512) {   // 8 b x 144 caps
            int b  = idx / 144;
            int cl = idx - b * 144;
            float* pp = &p_lds[b * 1152 + cl * 8];
            float sn = 0.f;
#pragma unroll
            for (int i = 0; i < NDIM; ++i) sn = fmaf(pp[i], pp[i], sn);
            float sc = sn / (1.f + sn) / sqrtf(sn + 1e-8f);
            float* ug = u + ((size_t)(b0 + b) * (NCAPS * NDIM) + (ch * 144 + cl) * 8);
            float4 u0 = make_float4(pp[0] * sc, pp[1] * sc, pp[2] * sc, pp[3] * sc);
            float4 u1 = make_float4(pp[4] * sc, pp[5] * sc, pp[6] * sc, pp[7] * sc);
            ((float4*)ug)[0] = u0;
            ((float4*)ug)[1] = u1;
        }
        __syncthreads();
    }
}

// ---------------- K4: u_hat + routing, 2 batches/block, 512 threads --------
__global__ __launch_bounds__(512, 4) void k_routing(const float* __restrict__ u,
                                                    const float* __restrict__ Wc,
                                                    float* __restrict__ out) {
    __shared__ float b_lds[2][NCAPS * 4];     // 9216 B
    __shared__ float c_lds[2][NCAPS * 4];     // 9216 B
    __shared__ float part_lds[2][512];        // 4096 B
    __shared__ float v_lds[2][64];            // 512 B

    int tid = threadIdx.x;
    int b0  = blockIdx.x * 2;

    int g = tid >> 6;
    int l = tid & 63;
    int d = l >> 4;
    int o = l & 15;
    int gu = __builtin_amdgcn_readfirstlane(g);   // wave-uniform -> s_load for u

    const float* ub0 = u + (size_t)(b0 + 0) * (NCAPS * NDIM) + gu * 36 * NDIM;
    const float* ub1 = u + (size_t)(b0 + 1) * (NCAPS * NDIM) + gu * 36 * NDIM;

    float uh0[36], uh1[36];
#pragma unroll
    for (int c = 0; c < 36; ++c) {
        int cap = gu * 36 + c;
        const float4* W4 = (const float4*)(Wc + ((size_t)cap * 512) + l * 8);
        float4 A  = W4[0];
        float4 Bv = W4[1];
        float t0 = A.x * ub0[c * 8 + 0];
        t0 = fmaf(A.y,  ub0[c * 8 + 1], t0);
        t0 = fmaf(A.z,  ub0[c * 8 + 2], t0);
        t0 = fmaf(A.w,  ub0[c * 8 + 3], t0);
        t0 = fmaf(Bv.x, ub0[c * 8 + 4], t0);
        t0 = fmaf(Bv.y, ub0[c * 8 + 5], t0);
        t0 = fmaf(Bv.z, ub0[c * 8 + 6], t0);
        t0 = fmaf(Bv.w, ub0[c * 8 + 7], t0);
        uh0[c] = t0;
        float t1 = A.x * ub1[c * 8 + 0];
        t1 = fmaf(A.y,  ub1[c * 8 + 1], t1);
        t1 = fmaf(A.z,  ub1[c * 8 + 2], t1);
        t1 = fmaf(A.w,  ub1[c * 8 + 3], t1);
        t1 = fmaf(Bv.x, ub1[c * 8 + 4], t1);
        t1 = fmaf(Bv.y, ub1[c * 8 + 5], t1);
        t1 = fmaf(Bv.z, ub1[c * 8 + 6], t1);
        t1 = fmaf(Bv.w, ub1[c * 8 + 7], t1);
        uh1[c] = t1;
    }

    for (int r = 0; r < 3; ++r) {
        if (r > 0) {
            __builtin_amdgcn_wave_barrier();
            for (int i = l; i < 72; i += 64) {
                int bb = (i >= 36) ? 1 : 0;
                int cl = i - bb * 36;
                int c  = gu * 36 + cl;
                float4 bv = *(const float4*)&b_lds[bb][c * 4];
                float m  = fmaxf(fmaxf(bv.x, bv.y), fmaxf(bv.z, bv.w));
                float e0 = expf(bv.x - m), e1 = expf(bv.y - m);
                float e2 = expf(bv.z - m), e3 = expf(bv.w - m);
                float inv = 1.f / (e0 + e1 + e2 + e3);
                e0 *= inv; e1 *= inv; e2 *= inv; e3 *= inv;
                *(float4*)&c_lds[bb][c * 4] = make_float4(e0, e1, e2, e3);
                if (r == 2) {
                    *(float4*)(out + 16384 + ((size_t)(b0 + bb) * NCAPS + c) * 4) =
                        make_float4(e0, e1, e2, e3);
                }
            }
            __builtin_amdgcn_wave_barrier();
        }

        float p0 = 0.f, p1 = 0.f;
        if (r == 0) {
#pragma unroll
            for (int c = 0; c < 36; ++c) {
                p0 = fmaf(0.25f, uh0[c], p0);
                p1 = fmaf(0.25f, uh1[c], p1);
            }
        } else {
#pragma unroll
            for (int c = 0; c < 36; ++c) {
                p0 = fmaf(c_lds[0][(g * 36 + c) * 4 + d], uh0[c], p0);
                p1 = fmaf(c_lds[1][(g * 36 + c) * 4 + d], uh1[c], p1);
            }
        }
        part_lds[0][tid] = p0;
        part_lds[1][tid] = p1;
        __syncthreads();

        if (tid < 128) {
            int bb = tid >> 6;
            int ll = tid & 63;
            float sv = 0.f;
#pragma unroll
            for (int k = 0; k < 8; ++k) sv += part_lds[bb][ll + 64 * k];
            float sq = rowsum16(sv * sv);
            float sc = sq / (1.f + sq) / sqrtf(sq + 1e-8f);
            float v  = sv * sc;
            v_lds[bb][ll] = v;
            if (r == 2) {
                float vv = rowsum16(v * v);
                if ((ll & 15) == 0)
                    out[(size_t)(b0 + bb) * 4 + (ll >> 4)] = sqrtf(vv);
            }
        }
        __syncthreads();

        if (r < 2) {
            float v0 = v_lds[0][l];
            float v1 = v_lds[1][l];
#pragma unroll
            for (int c = 0; c < 36; ++c) {
                float t0 = rowsum16(uh0[c] * v0);
                float t1 = rowsum16(uh1[c] * v1);
                if (o == 0) {
                    if (r == 0) {
                        b_lds[0][(g * 36 + c) * 4 + d] = t0;
                        b_lds[1][(g * 36 + c) * 4 + d] = t1;
                    } else {
                        b_lds[0][(g * 36 + c) * 4 + d] += t0;
                        b_lds[1][(g * 36 + c) * 4 + d] += t1;
                    }
                }
            }
        }
    }
}

extern "C" void kernel_launch(void* const* d_in, const int* in_sizes, int n_in,
                              void* d_out, int out_size, void* d_ws, size_t ws_size,
                              hipStream_t stream) {
    const float* x      = (const float*)d_in[0];
    const float* a      = (const float*)d_in[1];
    const float* w      = (const float*)d_in[2];
    const float* conv_w = (const float*)d_in[3];
    const float* conv_b = (const float*)d_in[4];
    const float* W_caps = (const float*)d_in[5];
    float* out = (float*)d_out;
    char* ws   = (char*)d_ws;

    __hip_bfloat16*  bwh  = (__hip_bfloat16*)(ws + BWH_OFF);
    __hip_bfloat16*  bwl  = (__hip_bfloat16*)(ws + BWL_OFF);
    __hip_bfloat16*  bph  = (__hip_bfloat16*)(ws + BPH_OFF);
    __hip_bfloat16*  bpl  = (__hip_bfloat16*)(ws + BPL_OFF);
    __hip_bfloat16*  h2hi = (__hip_bfloat16*)(ws + H2HI_OFF);
    __hip_bfloat16*  h2lo = (__hip_bfloat16*)(ws + H2LO_OFF);
    float*           u    = (float*)(ws + U_OFF);

    k_wav_pack<<<256, 256, 0, stream>>>(a, w, bwh, bwl);
    k_pack_b<<<2048, 256, 0, stream>>>(conv_w, bph, bpl);
    k_wavconv_mfma<<<BATCH / 8, 256, 0, stream>>>(x, bwh, bwl, h2hi, h2lo);
    k_conv_mfma<<<BATCH / 8, 512, 0, stream>>>(h2hi, h2lo, bph, bpl, conv_b, u);
    k_routing<<<BATCH / 2, 512, 0, stream>>>(u, W_caps, out);
}